// Round 5
// baseline (679.268 us; speedup 1.0000x reference)
//
#include <hip/hip_runtime.h>

typedef __attribute__((ext_vector_type(8))) short s16x8;
typedef __attribute__((ext_vector_type(8))) unsigned short u16x8;
typedef __attribute__((ext_vector_type(4))) float f32x4;

#define LN_EPS 1e-5f

__device__ inline float bf2f(unsigned short u) {
    union { unsigned int i; float f; } x; x.i = ((unsigned int)u) << 16; return x.f;
}
__device__ inline unsigned short f2bf(float f) {
    unsigned int u = __builtin_bit_cast(unsigned int, f);
    u += 0x7FFFu + ((u >> 16) & 1u);
    return (unsigned short)(u >> 16);
}
__device__ inline unsigned int cvt_pk_bf16(float lo, float hi) {
    unsigned int r;
    asm("v_cvt_pk_bf16_f32 %0, %1, %2" : "=v"(r) : "v"(lo), "v"(hi));
    return r;
}
__device__ inline s16x8 cvt_frag(float4 a, float4 b) {
    union { unsigned int u[4]; s16x8 s; } r;
    r.u[0] = cvt_pk_bf16(a.x, a.y);
    r.u[1] = cvt_pk_bf16(a.z, a.w);
    r.u[2] = cvt_pk_bf16(b.x, b.y);
    r.u[3] = cvt_pk_bf16(b.z, b.w);
    return r.s;
}

// ---------------------------------------------------------------------------
// B-direct GEMM: C[z] = A[z](bf16) @ W[z](f32)^T (+bias) (+ReLU), K=512 only.
// Block: 512 thr = 8 waves. Block tile = 64 rows x 256 cols; wave = 64r x 32c
// (4 m-frags x 2 n-frags of mfma_f32_16x16x32_bf16).
// A (64 rows x 512) staged once in LDS (XOR-swizzled), ONE barrier total.
// W fragments loaded directly global->VGPR (f32) + v_cvt_pk_bf16_f32; K-loop
// has NO barriers -> waves free-run; 2 blocks/CU via launch_bounds(512,4).
// ---------------------------------------------------------------------------
template<bool RELU>
__global__ __launch_bounds__(512, 4) void gemm_bdir_kernel(
    const unsigned short* __restrict__ A,
    const float* __restrict__ W,
    const float* __restrict__ bias1,
    const float* __restrict__ bias2,
    float bias_scale,
    unsigned short* __restrict__ C,
    int rows_total,
    size_t strideA_mode, size_t lda,
    size_t strideW_mode, size_t strideB_mode,
    size_t strideC_mode, size_t ldc)
{
    const int K = 512;
    const int z = blockIdx.z;
    const int r0 = blockIdx.y * 64;
    const int n0 = blockIdx.x * 256;

    __shared__ __align__(16) unsigned char As[64 * 1024];  // 64 rows x 512 bf16

    const int tid = threadIdx.x;
    const int lane = tid & 63, wid = tid >> 6;
    const int fr = lane & 15, ks = lane >> 4;

    // ---- stage A once (swizzled: byte = row*1024 + (slot*16 ^ ((row&7)<<4))) ----
    {
        const unsigned short* Az = A + (size_t)z * strideA_mode;
#pragma unroll
        for (int it = 0; it < 8; ++it) {
            const int idx = tid + it * 512;
            const int row = idx >> 6, slot = idx & 63;
            const int gr = min(r0 + row, rows_total - 1);
            u16x8 v = *(const u16x8*)(Az + (size_t)gr * lda + slot * 8);
            *(u16x8*)(&As[row * 1024 + ((slot * 16) ^ ((row & 7) << 4))]) = v;
        }
    }
    __syncthreads();

    // W row pointers for this wave's 2 col-fragments (row-major, K-contig)
    const float* __restrict__ Wr0 = W + (size_t)z * strideW_mode + (size_t)(n0 + wid * 32 + fr) * K + ks * 8;
    const float* __restrict__ Wr1 = Wr0 + (size_t)16 * K;

    f32x4 acc[4][2];
#pragma unroll
    for (int i = 0; i < 4; ++i)
#pragma unroll
        for (int j = 0; j < 2; ++j)
#pragma unroll
            for (int r = 0; r < 4; ++r) acc[i][j][r] = 0.f;

    // ---- K loop: 8 chunks of 64, fully unrolled, barrier-free ----
#pragma unroll
    for (int t = 0; t < 8; ++t) {
        float4 w00 = *(const float4*)(Wr0 + t * 64);
        float4 w01 = *(const float4*)(Wr0 + t * 64 + 4);
        float4 w02 = *(const float4*)(Wr0 + t * 64 + 32);
        float4 w03 = *(const float4*)(Wr0 + t * 64 + 36);
        float4 w10 = *(const float4*)(Wr1 + t * 64);
        float4 w11 = *(const float4*)(Wr1 + t * 64 + 4);
        float4 w12 = *(const float4*)(Wr1 + t * 64 + 32);
        float4 w13 = *(const float4*)(Wr1 + t * 64 + 36);

        s16x8 b00 = cvt_frag(w00, w01);   // n-frag 0, kk 0
        s16x8 b01 = cvt_frag(w02, w03);   // n-frag 0, kk 1
        s16x8 b10 = cvt_frag(w10, w11);   // n-frag 1, kk 0
        s16x8 b11 = cvt_frag(w12, w13);   // n-frag 1, kk 1

#pragma unroll
        for (int kk = 0; kk < 2; ++kk) {
            const int cb = t * 128 + kk * 64 + ks * 16;
            s16x8 af[4];
#pragma unroll
            for (int mi = 0; mi < 4; ++mi) {
                const int row = mi * 16 + fr;
                af[mi] = *(const s16x8*)(&As[row * 1024 + (cb ^ ((row & 7) << 4))]);
            }
            const s16x8 bk0 = kk ? b01 : b00;
            const s16x8 bk1 = kk ? b11 : b10;
#pragma unroll
            for (int mi = 0; mi < 4; ++mi) {
                acc[mi][0] = __builtin_amdgcn_mfma_f32_16x16x32_bf16(af[mi], bk0, acc[mi][0], 0, 0, 0);
                acc[mi][1] = __builtin_amdgcn_mfma_f32_16x16x32_bf16(af[mi], bk1, acc[mi][1], 0, 0, 0);
            }
        }
    }

    // ---- epilogue ----
#pragma unroll
    for (int ni = 0; ni < 2; ++ni) {
        const int col = n0 + wid * 32 + ni * 16 + fr;
        float bsum = 0.f;
        if (bias1) bsum += bias_scale * bias1[(size_t)z * strideB_mode + col];
        if (bias2) bsum += bias2[(size_t)z * strideB_mode + col];
#pragma unroll
        for (int mi = 0; mi < 4; ++mi) {
#pragma unroll
            for (int r = 0; r < 4; ++r) {
                const int row = r0 + mi * 16 + ks * 4 + r;
                if (row < rows_total) {
                    float v = acc[mi][ni][r] + bsum;
                    if (RELU) v = fmaxf(v, 0.f);
                    C[(size_t)z * strideC_mode + (size_t)row * ldc + col] = f2bf(v);
                }
            }
        }
    }
}

// ---------------------------------------------------------------------------
// Legacy 64x64 GEMM (only for the final [256,10000] K=256 f32-out GEMM)
// ---------------------------------------------------------------------------
template<bool RELU, bool F32OUT>
__global__ __launch_bounds__(256) void gemm_bt_kernel(
    const unsigned short* __restrict__ A,
    const float* __restrict__ W,
    const float* __restrict__ bias1,
    const float* __restrict__ bias2,
    float bias_scale,
    void* __restrict__ Cv,
    int N, int K,
    size_t strideA_mode, size_t lda,
    size_t strideW_mode,
    size_t strideB_mode,
    size_t strideC_mode, size_t ldc)
{
    const int m = blockIdx.z;
    const int n0 = blockIdx.x * 64;
    const int r0 = blockIdx.y * 64;
    const unsigned short* Am = A + (size_t)m * strideA_mode;
    const float* Wm = W + (size_t)m * strideW_mode;

    __shared__ __align__(16) unsigned short As[64][40];
    __shared__ __align__(16) unsigned short Bs[64][40];

    const int tid = threadIdx.x;
    const int lane = tid & 63, wid = tid >> 6;
    const int wr = (wid >> 1) * 32, wc = (wid & 1) * 32;
    const int fr = lane & 15, ks = lane >> 4;
    const int lrow = tid >> 2, lslot = tid & 3;

    f32x4 acc[2][2];
#pragma unroll
    for (int i = 0; i < 2; ++i)
#pragma unroll
        for (int j = 0; j < 2; ++j)
#pragma unroll
            for (int r = 0; r < 4; ++r) acc[i][j][r] = 0.f;

    const int bcol = n0 + lrow;
    for (int k0 = 0; k0 < K; k0 += 32) {
        u16x8 av = *(const u16x8*)(Am + (size_t)(r0 + lrow) * lda + k0 + lslot * 8);
        u16x8 bv;
#pragma unroll
        for (int i = 0; i < 8; ++i) bv[i] = 0;
        if (bcol < N) {
            const float* wp = Wm + (size_t)bcol * K + k0 + lslot * 8;
            float4 w0 = *(const float4*)(wp);
            float4 w1 = *(const float4*)(wp + 4);
            bv[0] = f2bf(w0.x); bv[1] = f2bf(w0.y); bv[2] = f2bf(w0.z); bv[3] = f2bf(w0.w);
            bv[4] = f2bf(w1.x); bv[5] = f2bf(w1.y); bv[6] = f2bf(w1.z); bv[7] = f2bf(w1.w);
        }
        __syncthreads();
        *(u16x8*)(&As[lrow][lslot * 8]) = av;
        *(u16x8*)(&Bs[lrow][lslot * 8]) = bv;
        __syncthreads();
        s16x8 a0 = *(const s16x8*)(&As[wr + fr][ks * 8]);
        s16x8 a1 = *(const s16x8*)(&As[wr + 16 + fr][ks * 8]);
        s16x8 b0 = *(const s16x8*)(&Bs[wc + fr][ks * 8]);
        s16x8 b1 = *(const s16x8*)(&Bs[wc + 16 + fr][ks * 8]);
        acc[0][0] = __builtin_amdgcn_mfma_f32_16x16x32_bf16(a0, b0, acc[0][0], 0, 0, 0);
        acc[0][1] = __builtin_amdgcn_mfma_f32_16x16x32_bf16(a0, b1, acc[0][1], 0, 0, 0);
        acc[1][0] = __builtin_amdgcn_mfma_f32_16x16x32_bf16(a1, b0, acc[1][0], 0, 0, 0);
        acc[1][1] = __builtin_amdgcn_mfma_f32_16x16x32_bf16(a1, b1, acc[1][1], 0, 0, 0);
    }

#pragma unroll
    for (int mi = 0; mi < 2; ++mi)
#pragma unroll
        for (int ni = 0; ni < 2; ++ni) {
            const int col = n0 + wc + ni * 16 + fr;
            if (col < N) {
                float bsum = 0.f;
                if (bias1) bsum += bias_scale * bias1[(size_t)m * strideB_mode + col];
                if (bias2) bsum += bias2[(size_t)m * strideB_mode + col];
#pragma unroll
                for (int r = 0; r < 4; ++r) {
                    const int row = r0 + wr + mi * 16 + ks * 4 + r;
                    float v = acc[mi][ni][r] + bsum;
                    if (RELU) v = fmaxf(v, 0.f);
                    const size_t idx = (size_t)m * strideC_mode + (size_t)row * ldc + col;
                    if (F32OUT) ((float*)Cv)[idx] = v;
                    else ((unsigned short*)Cv)[idx] = f2bf(v);
                }
            }
        }
}

// ---------------------------------------------------------------------------
// Embedding: e[b,d] = mean_s emb[x[b,s], d]
// ---------------------------------------------------------------------------
__global__ __launch_bounds__(512) void embed_kernel(
    const int* __restrict__ x, const float* __restrict__ emb,
    unsigned short* __restrict__ e)
{
    const int b = blockIdx.x;
    __shared__ int xs[128];
    const int tid = threadIdx.x;
    if (tid < 128) xs[tid] = x[b * 128 + tid];
    __syncthreads();
    float s = 0.f;
    for (int i = 0; i < 128; ++i) s += emb[(size_t)xs[i] * 512 + tid];
    e[(size_t)b * 512 + tid] = f2bf(s * (1.f / 128.f));
}

// ---------------------------------------------------------------------------
// Row LayerNorm over D=512 (+opt ReLU), gamma/beta f32, m = row % M.
// ---------------------------------------------------------------------------
template<bool RELU>
__global__ __launch_bounds__(256) void ln_kernel(
    const unsigned short* __restrict__ X,
    const float* __restrict__ G,
    const float* __restrict__ Bt,
    unsigned short* __restrict__ Y,
    int M)
{
    const int row = blockIdx.x;
    const int m = row % M;
    const unsigned short* xr = X + (size_t)row * 512;
    unsigned short* yr = Y + (size_t)row * 512;
    const int tid = threadIdx.x;
    const float x0 = bf2f(xr[tid]), x1 = bf2f(xr[tid + 256]);
    float s = x0 + x1, q = x0 * x0 + x1 * x1;
#pragma unroll
    for (int off = 32; off; off >>= 1) {
        s += __shfl_xor(s, off);
        q += __shfl_xor(q, off);
    }
    __shared__ float red[4][2];
    const int wid = tid >> 6, lane = tid & 63;
    if (lane == 0) { red[wid][0] = s; red[wid][1] = q; }
    __syncthreads();
    s = red[0][0] + red[1][0] + red[2][0] + red[3][0];
    q = red[0][1] + red[1][1] + red[2][1] + red[3][1];
    const float mu = s * (1.f / 512.f);
    const float var = q * (1.f / 512.f) - mu * mu;
    const float rstd = rsqrtf(var + LN_EPS);
    const float* g = G + (size_t)m * 512;
    const float* bt = Bt + (size_t)m * 512;
    float y0 = (x0 - mu) * rstd * g[tid] + bt[tid];
    float y1 = (x1 - mu) * rstd * g[tid + 256] + bt[tid + 256];
    if (RELU) { y0 = fmaxf(y0, 0.f); y1 = fmaxf(y1, 0.f); }
    yr[tid] = f2bf(y0);
    yr[tid + 256] = f2bf(y1);
}

// ---------------------------------------------------------------------------
// MFMA attention: one block per (b, h), full qkv buffer [256,150,1536].
// ---------------------------------------------------------------------------
#define KP 72
#define VP 168
__global__ __launch_bounds__(256) void attn_mfma_kernel(
    const unsigned short* __restrict__ qkv, unsigned short* __restrict__ o_att)
{
    const int b = blockIdx.x >> 3, h = blockIdx.x & 7;
    __shared__ __align__(16) unsigned short k_s[160 * KP];
    __shared__ __align__(16) unsigned short v_t[64 * VP];
    __shared__ __align__(16) unsigned short p_s[4][16 * VP];
    const int tid = threadIdx.x, lane = tid & 63, wid = tid >> 6;
    const int fr = lane & 15, ks = lane >> 4;
    const size_t base = (size_t)b * (150 * 1536) + h * 64;

    for (int idx = tid; idx < 160 * 8; idx += 256) {
        const int r = idx >> 3, c8 = (idx & 7) * 8;
        u16x8 v;
        if (r < 150) v = *(const u16x8*)(qkv + base + (size_t)r * 1536 + 512 + c8);
        else {
#pragma unroll
            for (int j = 0; j < 8; ++j) v[j] = 0;
        }
        *(u16x8*)(&k_s[r * KP + c8]) = v;
    }
    for (int idx = tid; idx < 160 * 8; idx += 256) {
        const int c8 = idx / 160, r = idx - c8 * 160;
        u16x8 v;
        if (r < 150) v = *(const u16x8*)(qkv + base + (size_t)r * 1536 + 1024 + c8 * 8);
        else {
#pragma unroll
            for (int j = 0; j < 8; ++j) v[j] = 0;
        }
#pragma unroll
        for (int j = 0; j < 8; ++j) v_t[(c8 * 8 + j) * VP + r] = v[j];
    }
    __syncthreads();

    unsigned short* pw = &p_s[wid][0];

    for (int qt = wid; qt < 10; qt += 4) {
        const int qr = (qt * 16 + fr < 150) ? qt * 16 + fr : 149;
        const unsigned short* qp = qkv + base + (size_t)qr * 1536;
        s16x8 qa0 = *(const s16x8*)(qp + ks * 8);
        s16x8 qa1 = *(const s16x8*)(qp + 32 + ks * 8);

        f32x4 acc[10];
#pragma unroll
        for (int t = 0; t < 10; ++t)
#pragma unroll
            for (int r = 0; r < 4; ++r) acc[t][r] = 0.f;
#pragma unroll
        for (int t = 0; t < 10; ++t) {
            s16x8 kb0 = *(const s16x8*)(&k_s[(t * 16 + fr) * KP + ks * 8]);
            s16x8 kb1 = *(const s16x8*)(&k_s[(t * 16 + fr) * KP + 32 + ks * 8]);
            acc[t] = __builtin_amdgcn_mfma_f32_16x16x32_bf16(qa0, kb0, acc[t], 0, 0, 0);
            acc[t] = __builtin_amdgcn_mfma_f32_16x16x32_bf16(qa1, kb1, acc[t], 0, 0, 0);
        }

        const bool v9 = (fr < 6);
        float inv[4];
#pragma unroll
        for (int i = 0; i < 4; ++i) {
            float m = -1e30f;
#pragma unroll
            for (int t = 0; t < 9; ++t) m = fmaxf(m, acc[t][i]);
            if (v9) m = fmaxf(m, acc[9][i]);
#pragma unroll
            for (int off = 1; off < 16; off <<= 1) m = fmaxf(m, __shfl_xor(m, off));
            float s = 0.f;
#pragma unroll
            for (int t = 0; t < 10; ++t) {
                float e = 0.f;
                if (t < 9 || v9) e = __expf(0.125f * (acc[t][i] - m));
                s += e;
                pw[(ks * 4 + i) * VP + t * 16 + fr] = f2bf(e);
            }
#pragma unroll
            for (int off = 1; off < 16; off <<= 1) s += __shfl_xor(s, off);
            inv[i] = 1.f / s;
        }

        f32x4 o[4];
#pragma unroll
        for (int dt = 0; dt < 4; ++dt)
#pragma unroll
            for (int r = 0; r < 4; ++r) o[dt][r] = 0.f;
#pragma unroll
        for (int kc = 0; kc < 5; ++kc) {
            s16x8 pa = *(const s16x8*)(&pw[fr * VP + kc * 32 + ks * 8]);
#pragma unroll
            for (int dt = 0; dt < 4; ++dt) {
                s16x8 vb = *(const s16x8*)(&v_t[(dt * 16 + fr) * VP + kc * 32 + ks * 8]);
                o[dt] = __builtin_amdgcn_mfma_f32_16x16x32_bf16(pa, vb, o[dt], 0, 0, 0);
            }
        }

#pragma unroll
        for (int dt = 0; dt < 4; ++dt) {
            const int d = h * 64 + dt * 16 + fr;
#pragma unroll
            for (int i = 0; i < 4; ++i) {
                const int q = qt * 16 + ks * 4 + i;
                if (q < 150)
                    o_att[((size_t)(b * 150 + q)) * 512 + d] = f2bf(o[dt][i] * inv[i]);
            }
        }
    }
}

// ---------------------------------------------------------------------------
// osum[b,d] = sum_m o_att[b,m,d]
// ---------------------------------------------------------------------------
__global__ __launch_bounds__(512) void osum_kernel(
    const unsigned short* __restrict__ o_att, unsigned short* __restrict__ osum)
{
    const int b = blockIdx.x, tid = threadIdx.x;
    float s = 0.f;
    const unsigned short* p = o_att + (size_t)b * 150 * 512 + tid;
    for (int mm = 0; mm < 150; ++mm) s += bf2f(p[(size_t)mm * 512]);
    osum[(size_t)b * 512 + tid] = f2bf(s);
}

// ---------------------------------------------------------------------------
extern "C" void kernel_launch(void* const* d_in, const int* in_sizes, int n_in,
                              void* d_out, int out_size, void* d_ws, size_t ws_size,
                              hipStream_t stream)
{
    (void)in_sizes; (void)n_in; (void)out_size; (void)ws_size;

    const int*   x          = (const int*)d_in[0];
    const float* emb        = (const float*)d_in[1];
    const float* W1         = (const float*)d_in[2];
    const float* b1         = (const float*)d_in[3];
    const float* ln1_g      = (const float*)d_in[4];
    const float* ln1_b      = (const float*)d_in[5];
    const float* W2         = (const float*)d_in[6];
    const float* b2         = (const float*)d_in[7];
    const float* dbias      = (const float*)d_in[8];
    const float* in_proj_w  = (const float*)d_in[9];
    const float* in_proj_b  = (const float*)d_in[10];
    const float* out_proj_w = (const float*)d_in[11];
    const float* out_proj_b = (const float*)d_in[12];
    const float* norm_g     = (const float*)d_in[13];
    const float* norm_b     = (const float*)d_in[14];
    const float* dec_w1     = (const float*)d_in[15];
    const float* dec_b1     = (const float*)d_in[16];
    const float* dec_w2     = (const float*)d_in[17];
    const float* dec_b2     = (const float*)d_in[18];

    char* ws = (char*)d_ws;
    unsigned short* e_bf  = (unsigned short*)(ws + 0x0);        // [256,512] bf16
    unsigned short* osum  = (unsigned short*)(ws + 0x40000);
    unsigned short* att1  = (unsigned short*)(ws + 0x80000);
    unsigned short* agg   = (unsigned short*)(ws + 0xC0000);
    unsigned short* dec1  = (unsigned short*)(ws + 0x100000);
    unsigned short* h1    = (unsigned short*)(ws + 0x200000);   // [B,M,D] 37.5MB (later o_att)
    unsigned short* mo    = (unsigned short*)(ws + 0x2800000);  // [B,M,D] 37.5MB
    unsigned short* qkvf  = (unsigned short*)(ws + 0x4E00000);  // [B,M,3D] 112.5MB
    unsigned short* o_att = h1;                                  // h1 dead after G2

    // 1) embedding mean -> e [256,512]
    embed_kernel<<<256, 512, 0, stream>>>(x, emb, e_bf);

    // 2) G1: h1[b,m,:] = e[b,:] @ W1[m]^T + b1[m]
    gemm_bdir_kernel<false><<<dim3(2, 4, 150), 512, 0, stream>>>(
        e_bf, W1, b1, nullptr, 1.f, h1,
        256, (size_t)0, 512, (size_t)512 * 512, 512, 512, 76800);

    // 3) LN(ln1_g, ln1_b) + ReLU, in-place on h1
    ln_kernel<true><<<38400, 256, 0, stream>>>(h1, ln1_g, ln1_b, h1, 150);

    // 4) G2: mo[b,m,:] = h1[b,m,:] @ W2[m]^T + b2[m] + dbias[m]
    gemm_bdir_kernel<false><<<dim3(2, 4, 150), 512, 0, stream>>>(
        h1, W2, b2, dbias, 1.f, mo,
        256, (size_t)512, 76800, (size_t)512 * 512, 512, 512, 76800);

    // 5) qkv = mo @ in_proj_w^T + in_proj_b  ([38400,512] x [1536,512]^T, one launch)
    gemm_bdir_kernel<false><<<dim3(6, 600, 1), 512, 0, stream>>>(
        mo, in_proj_w, in_proj_b, nullptr, 1.f, qkvf,
        38400, (size_t)0, 512, (size_t)0, 0, 0, 1536);

    // 6) attention per (b,h) -> o_att
    attn_mfma_kernel<<<2048, 256, 0, stream>>>(qkvf, o_att);

    // 7) osum[b,:] = sum_m o_att[b,m,:]
    osum_kernel<<<256, 512, 0, stream>>>(o_att, osum);

    // 8) attended_sum = osum @ out_proj_w^T + 150*out_proj_b
    gemm_bdir_kernel<false><<<dim3(2, 4, 1), 512, 0, stream>>>(
        osum, out_proj_w, out_proj_b, nullptr, 150.f, att1,
        256, (size_t)0, 512, (size_t)0, 0, 0, 512);

    // 9) agg = LN(attended_sum; norm_g, norm_b)
    ln_kernel<false><<<256, 256, 0, stream>>>(att1, norm_g, norm_b, agg, 1);

    // 10) dec1 = ReLU(agg @ dec_w1^T + dec_b1)   [256,256]
    gemm_bdir_kernel<true><<<dim3(1, 4, 1), 512, 0, stream>>>(
        agg, dec_w1, dec_b1, nullptr, 1.f, dec1,
        256, (size_t)0, 512, (size_t)0, 0, 0, 256);

    // 11) out = dec1 @ dec_w2^T + dec_b2   [256,10000] f32 (K=256)
    gemm_bt_kernel<false, true><<<dim3(157, 4, 1), 256, 0, stream>>>(
        dec1, dec_w2, dec_b2, nullptr, 1.f, d_out,
        10000, 256, (size_t)0, 256, (size_t)0, 0, 0, 10000);
}

// Round 6
// 669.857 us; speedup vs baseline: 1.0140x; 1.0140x over previous
//
#include <hip/hip_runtime.h>

typedef __attribute__((ext_vector_type(8))) short s16x8;
typedef __attribute__((ext_vector_type(8))) unsigned short u16x8;
typedef __attribute__((ext_vector_type(4))) float f32x4;
typedef __attribute__((ext_vector_type(2))) unsigned int u32x2;

#define LN_EPS 1e-5f

__device__ inline float bf2f(unsigned short u) {
    union { unsigned int i; float f; } x; x.i = ((unsigned int)u) << 16; return x.f;
}
__device__ inline unsigned short f2bf(float f) {
    unsigned int u = __builtin_bit_cast(unsigned int, f);
    u += 0x7FFFu + ((u >> 16) & 1u);
    return (unsigned short)(u >> 16);
}
__device__ inline unsigned int cvt_pk_bf16(float lo, float hi) {
    unsigned int r;
    asm("v_cvt_pk_bf16_f32 %0, %1, %2" : "=v"(r) : "v"(lo), "v"(hi));
    return r;
}

// ---------------------------------------------------------------------------
// W-resident GEMM: C[z] = A[z](bf16, small/L2-hot) @ W[z](f32, streamed)^T
//   (+bias_scale*bias1+bias2) (+ReLU) (f32 or bf16 out)
// Block = 256 thr (4 waves). Tile: 256 A-rows x 32 W-rows, FULL K in LDS.
// Staging: 32xK W-rows f32->bf16->LDS, each 2KB row read contiguously by 128
// threads (perfect HBM coalescing), XOR-swizzled within 128B windows. ONE
// barrier/block. K-loop barrier-free: A-frags direct global->VGPR (L1/L2 hot,
// 64B sectors), 2-deep register double-buffer, 8 MFMA/k-step per wave.
// Bijective XCD swizzle clusters same-z blocks on one XCD (L2 A-slab reuse).
// ---------------------------------------------------------------------------
template<int K, bool RELU, bool F32OUT>
__global__ __launch_bounds__(256, 4) void gemm_wres_kernel(
    const unsigned short* __restrict__ A,
    const float* __restrict__ W,
    const float* __restrict__ bias1,
    const float* __restrict__ bias2,
    float bias_scale,
    void* __restrict__ Cv,
    int N, int rows_total,
    int gx, int gy,
    size_t strideA_mode, size_t lda,
    size_t strideW_mode, size_t strideB_mode,
    size_t strideC_mode, size_t ldc)
{
    // ---- bijective XCD-aware block remap (8 XCDs) ----
    const int nwg = gridDim.x;
    const int wgid = blockIdx.x;
    const int q8 = nwg >> 3, r8 = nwg & 7;
    const int xcd = wgid & 7, sub = wgid >> 3;
    int p = (xcd < r8 ? xcd * (q8 + 1) : r8 * (q8 + 1) + (xcd - r8) * q8) + sub;
    const int bx = p % gx; p /= gx;
    const int by = p % gy;
    const int bz = p / gy;

    const int n0 = bx * 32;
    const int r0 = by * 256;

    __shared__ __align__(16) unsigned char blds[32 * K * 2];

    const int tid = threadIdx.x;
    const int lane = tid & 63, wid = tid >> 6;
    const int fr = lane & 15, ks = lane >> 4;

    // ---- stage W tile: rows n0..n0+31, all K, f32 -> bf16, swizzled ----
    {
        constexpr int F4R = K >> 2;             // float4 per row
        constexpr int ITERS = (32 * F4R) / 256;
        const float* Wz = W + (size_t)bz * strideW_mode + (size_t)n0 * K;
#pragma unroll
        for (int it = 0; it < ITERS; ++it) {
            const int i = tid + it * 256;
            const int row = i / F4R;
            const int cf = i % F4R;
            float4 w = make_float4(0.f, 0.f, 0.f, 0.f);
            if (n0 + row < N) w = *(const float4*)(Wz + (size_t)row * K + (cf << 2));
            u32x2 val;
            val[0] = cvt_pk_bf16(w.x, w.y);
            val[1] = cvt_pk_bf16(w.z, w.w);
            const int cb = cf << 3;
            const int sw = (cb & ~127) | ((cb ^ ((row & 7) << 4)) & 127);
            *(u32x2*)(&blds[row * (K * 2) + sw]) = val;
        }
    }
    __syncthreads();

    // ---- A-row pointers (clamped), k-offset ks*8 ----
    const unsigned short* ap[4];
#pragma unroll
    for (int mi = 0; mi < 4; ++mi) {
        int grow = r0 + wid * 64 + mi * 16 + fr;
        grow = min(grow, rows_total - 1);
        ap[mi] = A + (size_t)bz * strideA_mode + (size_t)grow * lda + ks * 8;
    }

    f32x4 acc[4][2];
#pragma unroll
    for (int i = 0; i < 4; ++i)
#pragma unroll
        for (int j = 0; j < 2; ++j)
#pragma unroll
            for (int r = 0; r < 4; ++r) acc[i][j][r] = 0.f;

    auto ldb = [&](int ni, int t) -> s16x8 {
        const int row = ni * 16 + fr;
        const int cb = t * 64 + ks * 16;
        const int sw = (cb & ~127) | ((cb ^ ((row & 7) << 4)) & 127);
        return *(const s16x8*)(&blds[row * (K * 2) + sw]);
    };

    constexpr int KS = K >> 5;
    s16x8 areg[2][4];
    s16x8 breg[2][2];
#pragma unroll
    for (int mi = 0; mi < 4; ++mi) areg[0][mi] = *(const s16x8*)(ap[mi]);
    breg[0][0] = ldb(0, 0);
    breg[0][1] = ldb(1, 0);

#pragma unroll
    for (int t = 0; t < KS; ++t) {
        const int cur = t & 1, nxt = cur ^ 1;
        if (t + 1 < KS) {
#pragma unroll
            for (int mi = 0; mi < 4; ++mi)
                areg[nxt][mi] = *(const s16x8*)(ap[mi] + (t + 1) * 32);
            breg[nxt][0] = ldb(0, t + 1);
            breg[nxt][1] = ldb(1, t + 1);
        }
#pragma unroll
        for (int mi = 0; mi < 4; ++mi) {
            acc[mi][0] = __builtin_amdgcn_mfma_f32_16x16x32_bf16(areg[cur][mi], breg[cur][0], acc[mi][0], 0, 0, 0);
            acc[mi][1] = __builtin_amdgcn_mfma_f32_16x16x32_bf16(areg[cur][mi], breg[cur][1], acc[mi][1], 0, 0, 0);
        }
    }

    // ---- epilogue ----
#pragma unroll
    for (int ni = 0; ni < 2; ++ni) {
        const int col = n0 + ni * 16 + fr;
        if (col < N) {
            float bsum = 0.f;
            if (bias1) bsum += bias_scale * bias1[(size_t)bz * strideB_mode + col];
            if (bias2) bsum += bias2[(size_t)bz * strideB_mode + col];
#pragma unroll
            for (int mi = 0; mi < 4; ++mi) {
#pragma unroll
                for (int r = 0; r < 4; ++r) {
                    const int row = r0 + wid * 64 + mi * 16 + ks * 4 + r;
                    if (row < rows_total) {
                        float v = acc[mi][ni][r] + bsum;
                        if (RELU) v = fmaxf(v, 0.f);
                        const size_t idx = (size_t)bz * strideC_mode + (size_t)row * ldc + col;
                        if (F32OUT) ((float*)Cv)[idx] = v;
                        else ((unsigned short*)Cv)[idx] = f2bf(v);
                    }
                }
            }
        }
    }
}

// ---------------------------------------------------------------------------
// Embedding: e[b,d] = mean_s emb[x[b,s], d]
// ---------------------------------------------------------------------------
__global__ __launch_bounds__(512) void embed_kernel(
    const int* __restrict__ x, const float* __restrict__ emb,
    unsigned short* __restrict__ e)
{
    const int b = blockIdx.x;
    __shared__ int xs[128];
    const int tid = threadIdx.x;
    if (tid < 128) xs[tid] = x[b * 128 + tid];
    __syncthreads();
    float s = 0.f;
    for (int i = 0; i < 128; ++i) s += emb[(size_t)xs[i] * 512 + tid];
    e[(size_t)b * 512 + tid] = f2bf(s * (1.f / 128.f));
}

// ---------------------------------------------------------------------------
// Row LayerNorm over D=512 (+opt ReLU), gamma/beta f32, m = row % M.
// ---------------------------------------------------------------------------
template<bool RELU>
__global__ __launch_bounds__(256) void ln_kernel(
    const unsigned short* __restrict__ X,
    const float* __restrict__ G,
    const float* __restrict__ Bt,
    unsigned short* __restrict__ Y,
    int M)
{
    const int row = blockIdx.x;
    const int m = row % M;
    const unsigned short* xr = X + (size_t)row * 512;
    unsigned short* yr = Y + (size_t)row * 512;
    const int tid = threadIdx.x;
    const float x0 = bf2f(xr[tid]), x1 = bf2f(xr[tid + 256]);
    float s = x0 + x1, q = x0 * x0 + x1 * x1;
#pragma unroll
    for (int off = 32; off; off >>= 1) {
        s += __shfl_xor(s, off);
        q += __shfl_xor(q, off);
    }
    __shared__ float red[4][2];
    const int wid = tid >> 6, lane = tid & 63;
    if (lane == 0) { red[wid][0] = s; red[wid][1] = q; }
    __syncthreads();
    s = red[0][0] + red[1][0] + red[2][0] + red[3][0];
    q = red[0][1] + red[1][1] + red[2][1] + red[3][1];
    const float mu = s * (1.f / 512.f);
    const float var = q * (1.f / 512.f) - mu * mu;
    const float rstd = rsqrtf(var + LN_EPS);
    const float* g = G + (size_t)m * 512;
    const float* bt = Bt + (size_t)m * 512;
    float y0 = (x0 - mu) * rstd * g[tid] + bt[tid];
    float y1 = (x1 - mu) * rstd * g[tid + 256] + bt[tid + 256];
    if (RELU) { y0 = fmaxf(y0, 0.f); y1 = fmaxf(y1, 0.f); }
    yr[tid] = f2bf(y0);
    yr[tid + 256] = f2bf(y1);
}

// ---------------------------------------------------------------------------
// MFMA attention: one block per (b, h), qkv [256,150,1536] bf16.
// ---------------------------------------------------------------------------
#define KP 72
#define VP 168
__global__ __launch_bounds__(256) void attn_mfma_kernel(
    const unsigned short* __restrict__ qkv, unsigned short* __restrict__ o_att)
{
    const int b = blockIdx.x >> 3, h = blockIdx.x & 7;
    __shared__ __align__(16) unsigned short k_s[160 * KP];
    __shared__ __align__(16) unsigned short v_t[64 * VP];
    __shared__ __align__(16) unsigned short p_s[4][16 * VP];
    const int tid = threadIdx.x, lane = tid & 63, wid = tid >> 6;
    const int fr = lane & 15, ks = lane >> 4;
    const size_t base = (size_t)b * (150 * 1536) + h * 64;

    for (int idx = tid; idx < 160 * 8; idx += 256) {
        const int r = idx >> 3, c8 = (idx & 7) * 8;
        u16x8 v;
        if (r < 150) v = *(const u16x8*)(qkv + base + (size_t)r * 1536 + 512 + c8);
        else {
#pragma unroll
            for (int j = 0; j < 8; ++j) v[j] = 0;
        }
        *(u16x8*)(&k_s[r * KP + c8]) = v;
    }
    for (int idx = tid; idx < 160 * 8; idx += 256) {
        const int c8 = idx / 160, r = idx - c8 * 160;
        u16x8 v;
        if (r < 150) v = *(const u16x8*)(qkv + base + (size_t)r * 1536 + 1024 + c8 * 8);
        else {
#pragma unroll
            for (int j = 0; j < 8; ++j) v[j] = 0;
        }
#pragma unroll
        for (int j = 0; j < 8; ++j) v_t[(c8 * 8 + j) * VP + r] = v[j];
    }
    __syncthreads();

    unsigned short* pw = &p_s[wid][0];

    for (int qt = wid; qt < 10; qt += 4) {
        const int qr = (qt * 16 + fr < 150) ? qt * 16 + fr : 149;
        const unsigned short* qp = qkv + base + (size_t)qr * 1536;
        s16x8 qa0 = *(const s16x8*)(qp + ks * 8);
        s16x8 qa1 = *(const s16x8*)(qp + 32 + ks * 8);

        f32x4 acc[10];
#pragma unroll
        for (int t = 0; t < 10; ++t)
#pragma unroll
            for (int r = 0; r < 4; ++r) acc[t][r] = 0.f;
#pragma unroll
        for (int t = 0; t < 10; ++t) {
            s16x8 kb0 = *(const s16x8*)(&k_s[(t * 16 + fr) * KP + ks * 8]);
            s16x8 kb1 = *(const s16x8*)(&k_s[(t * 16 + fr) * KP + 32 + ks * 8]);
            acc[t] = __builtin_amdgcn_mfma_f32_16x16x32_bf16(qa0, kb0, acc[t], 0, 0, 0);
            acc[t] = __builtin_amdgcn_mfma_f32_16x16x32_bf16(qa1, kb1, acc[t], 0, 0, 0);
        }

        const bool v9 = (fr < 6);
        float inv[4];
#pragma unroll
        for (int i = 0; i < 4; ++i) {
            float m = -1e30f;
#pragma unroll
            for (int t = 0; t < 9; ++t) m = fmaxf(m, acc[t][i]);
            if (v9) m = fmaxf(m, acc[9][i]);
#pragma unroll
            for (int off = 1; off < 16; off <<= 1) m = fmaxf(m, __shfl_xor(m, off));
            float s = 0.f;
#pragma unroll
            for (int t = 0; t < 10; ++t) {
                float e = 0.f;
                if (t < 9 || v9) e = __expf(0.125f * (acc[t][i] - m));
                s += e;
                pw[(ks * 4 + i) * VP + t * 16 + fr] = f2bf(e);
            }
#pragma unroll
            for (int off = 1; off < 16; off <<= 1) s += __shfl_xor(s, off);
            inv[i] = 1.f / s;
        }

        f32x4 o[4];
#pragma unroll
        for (int dt = 0; dt < 4; ++dt)
#pragma unroll
            for (int r = 0; r < 4; ++r) o[dt][r] = 0.f;
#pragma unroll
        for (int kc = 0; kc < 5; ++kc) {
            s16x8 pa = *(const s16x8*)(&pw[fr * VP + kc * 32 + ks * 8]);
#pragma unroll
            for (int dt = 0; dt < 4; ++dt) {
                s16x8 vb = *(const s16x8*)(&v_t[(dt * 16 + fr) * VP + kc * 32 + ks * 8]);
                o[dt] = __builtin_amdgcn_mfma_f32_16x16x32_bf16(pa, vb, o[dt], 0, 0, 0);
            }
        }

#pragma unroll
        for (int dt = 0; dt < 4; ++dt) {
            const int d = h * 64 + dt * 16 + fr;
#pragma unroll
            for (int i = 0; i < 4; ++i) {
                const int q = qt * 16 + ks * 4 + i;
                if (q < 150)
                    o_att[((size_t)(b * 150 + q)) * 512 + d] = f2bf(o[dt][i] * inv[i]);
            }
        }
    }
}

// ---------------------------------------------------------------------------
// osum[b,d] = sum_m o_att[b,m,d]
// ---------------------------------------------------------------------------
__global__ __launch_bounds__(512) void osum_kernel(
    const unsigned short* __restrict__ o_att, unsigned short* __restrict__ osum)
{
    const int b = blockIdx.x, tid = threadIdx.x;
    float s = 0.f;
    const unsigned short* p = o_att + (size_t)b * 150 * 512 + tid;
    for (int mm = 0; mm < 150; ++mm) s += bf2f(p[(size_t)mm * 512]);
    osum[(size_t)b * 512 + tid] = f2bf(s);
}

// ---------------------------------------------------------------------------
extern "C" void kernel_launch(void* const* d_in, const int* in_sizes, int n_in,
                              void* d_out, int out_size, void* d_ws, size_t ws_size,
                              hipStream_t stream)
{
    (void)in_sizes; (void)n_in; (void)out_size; (void)ws_size;

    const int*   x          = (const int*)d_in[0];
    const float* emb        = (const float*)d_in[1];
    const float* W1         = (const float*)d_in[2];
    const float* b1         = (const float*)d_in[3];
    const float* ln1_g      = (const float*)d_in[4];
    const float* ln1_b      = (const float*)d_in[5];
    const float* W2         = (const float*)d_in[6];
    const float* b2         = (const float*)d_in[7];
    const float* dbias      = (const float*)d_in[8];
    const float* in_proj_w  = (const float*)d_in[9];
    const float* in_proj_b  = (const float*)d_in[10];
    const float* out_proj_w = (const float*)d_in[11];
    const float* out_proj_b = (const float*)d_in[12];
    const float* norm_g     = (const float*)d_in[13];
    const float* norm_b     = (const float*)d_in[14];
    const float* dec_w1     = (const float*)d_in[15];
    const float* dec_b1     = (const float*)d_in[16];
    const float* dec_w2     = (const float*)d_in[17];
    const float* dec_b2     = (const float*)d_in[18];

    char* ws = (char*)d_ws;
    unsigned short* e_bf  = (unsigned short*)(ws + 0x0);        // [256,512] bf16
    unsigned short* osum  = (unsigned short*)(ws + 0x40000);
    unsigned short* att1  = (unsigned short*)(ws + 0x80000);
    unsigned short* agg   = (unsigned short*)(ws + 0xC0000);
    unsigned short* dec1  = (unsigned short*)(ws + 0x100000);
    unsigned short* h1    = (unsigned short*)(ws + 0x200000);   // [B,M,D] 37.5MB (later o_att)
    unsigned short* mo    = (unsigned short*)(ws + 0x2800000);  // [B,M,D] 37.5MB
    unsigned short* qkvf  = (unsigned short*)(ws + 0x4E00000);  // [B,M,3D] 112.5MB
    unsigned short* o_att = h1;

    // 1) embedding mean -> e [256,512]
    embed_kernel<<<256, 512, 0, stream>>>(x, emb, e_bf);

    // 2) G1: h1[b,m,:] = e[b,:] @ W1[m]^T + b1[m]   grid: gx=16, gy=1, gz=150
    gemm_wres_kernel<512, false, false><<<16 * 1 * 150, 256, 0, stream>>>(
        e_bf, W1, b1, nullptr, 1.f, h1,
        512, 256, 16, 1,
        (size_t)0, 512, (size_t)512 * 512, 512, 512, 76800);

    // 3) LN(ln1_g, ln1_b) + ReLU, in-place on h1
    ln_kernel<true><<<38400, 256, 0, stream>>>(h1, ln1_g, ln1_b, h1, 150);

    // 4) G2: mo = h1 @ W2^T + b2 + dbias
    gemm_wres_kernel<512, false, false><<<16 * 1 * 150, 256, 0, stream>>>(
        h1, W2, b2, dbias, 1.f, mo,
        512, 256, 16, 1,
        (size_t)512, 76800, (size_t)512 * 512, 512, 512, 76800);

    // 5) qkv = mo @ in_proj_w^T + in_proj_b   grid: gx=48, gy=150, gz=1
    gemm_wres_kernel<512, false, false><<<48 * 150, 256, 0, stream>>>(
        mo, in_proj_w, in_proj_b, nullptr, 1.f, qkvf,
        1536, 38400, 48, 150,
        (size_t)0, 512, (size_t)0, 0, 0, 1536);

    // 6) attention per (b,h) -> o_att
    attn_mfma_kernel<<<2048, 256, 0, stream>>>(qkvf, o_att);

    // 7) osum[b,:] = sum_m o_att[b,m,:]
    osum_kernel<<<256, 512, 0, stream>>>(o_att, osum);

    // 8) attended_sum = osum @ out_proj_w^T + 150*out_proj_b
    gemm_wres_kernel<512, false, false><<<16, 256, 0, stream>>>(
        osum, out_proj_w, out_proj_b, nullptr, 150.f, att1,
        512, 256, 16, 1,
        (size_t)0, 512, (size_t)0, 0, 0, 512);

    // 9) agg = LN(attended_sum; norm_g, norm_b)
    ln_kernel<false><<<256, 256, 0, stream>>>(att1, norm_g, norm_b, agg, 1);

    // 10) dec1 = ReLU(agg @ dec_w1^T + dec_b1)   [256,256]
    gemm_wres_kernel<512, true, false><<<8, 256, 0, stream>>>(
        agg, dec_w1, dec_b1, nullptr, 1.f, dec1,
        256, 256, 8, 1,
        (size_t)0, 512, (size_t)0, 0, 0, 256);

    // 11) out = dec1 @ dec_w2^T + dec_b2   [256,10000] f32, K=256
    gemm_wres_kernel<256, false, true><<<313, 256, 0, stream>>>(
        dec1, dec_w2, dec_b2, nullptr, 1.f, d_out,
        10000, 256, 313, 1,
        (size_t)0, 256, (size_t)0, 0, 0, 10000);
}

// Round 7
// 508.302 us; speedup vs baseline: 1.3363x; 1.3178x over previous
//
#include <hip/hip_runtime.h>

typedef __attribute__((ext_vector_type(8))) short s16x8;
typedef __attribute__((ext_vector_type(8))) unsigned short u16x8;
typedef __attribute__((ext_vector_type(4))) float f32x4;

#define LN_EPS 1e-5f

__device__ inline float bf2f(unsigned short u) {
    union { unsigned int i; float f; } x; x.i = ((unsigned int)u) << 16; return x.f;
}
__device__ inline unsigned short f2bf(float f) {
    unsigned int u = __builtin_bit_cast(unsigned int, f);
    u += 0x7FFFu + ((u >> 16) & 1u);
    return (unsigned short)(u >> 16);
}
__device__ inline unsigned int cvt_pk_bf16(float lo, float hi) {
    unsigned int r;
    asm("v_cvt_pk_bf16_f32 %0, %1, %2" : "=v"(r) : "v"(lo), "v"(hi));
    return r;
}
typedef __attribute__((address_space(1))) const unsigned int as1_u32;
typedef __attribute__((address_space(3))) unsigned int as3_u32;
__device__ inline void gl2lds16(const void* g, void* l) {
    __builtin_amdgcn_global_load_lds((as1_u32*)g, (as3_u32*)l, 16, 0, 0);
}

// ---------------------------------------------------------------------------
// 2-phase pipelined GEMM (m97/T3 structure): C[z] = A[z](bf16) @ W[z](f32)^T
//   (+bias_scale*bias1 + bias2) (+ReLU), bf16 or f32 out.
// 256 thr = 4 waves; tile 128(M) x 128(N); BK=64; LDS 2 x (A 16K + B 16K).
// A staged via global_load_lds w=16, source pre-XOR-swizzled (rule #21).
// W reg-staged (T14 issue-early/write-late): 8x dwordx4 -> cvt_pk_bf16 ->
// swizzled ds_write. One barrier per K-step; prefetch stays in flight across
// the compute phase. M must be a multiple of 128; N guarded.
// ---------------------------------------------------------------------------
template<int K, bool RELU, bool F32OUT>
__global__ __launch_bounds__(256, 2) void gemm128_kernel(
    const unsigned short* __restrict__ A,
    const float* __restrict__ W,
    const float* __restrict__ bias1,
    const float* __restrict__ bias2,
    float bias_scale,
    void* __restrict__ Cv,
    int N, int gx, int gy,
    size_t strideA_mode, size_t lda,
    size_t strideW_mode, size_t strideB_mode,
    size_t strideC_mode, size_t ldc)
{
    constexpr int NSTEP = K / 64;

    // bijective XCD-aware remap (m204): consecutive p share row-panel (L2)
    const int nwg = gridDim.x, wgid = blockIdx.x;
    const int q8 = nwg >> 3, r8 = nwg & 7;
    const int xcd = wgid & 7, sub = wgid >> 3;
    int p = (xcd < r8 ? xcd * (q8 + 1) : r8 * (q8 + 1) + (xcd - r8) * q8) + sub;
    const int bx = p % gx; p /= gx;
    const int by = p % gy;
    const int bz = p / gy;
    const int n0 = bx * 128, r0 = by * 128;

    __shared__ __align__(16) unsigned char lds[2][32768];  // [A 16K | B 16K]

    const int tid = threadIdx.x, lane = tid & 63, wid = tid >> 6;
    const int fr = lane & 15, ks = lane >> 4;
    const int wr = (wid >> 1) * 64, wc = (wid & 1) * 64;

    // ---- A source address (per-lane, inverse-swizzled column) ----
    const int a_row = wid * 32 + (lane >> 3);   // + j*8 per issue
    const int a_cs = lane & 7;
    const unsigned char* aG = (const unsigned char*)A
        + ((size_t)bz * strideA_mode + (size_t)(r0 + a_row) * lda) * 2
        + (size_t)((a_cs * 16) ^ ((a_row & 7) << 4));
    const size_t a_jstep = (size_t)8 * lda * 2;

    // ---- W staging coords: 2 threads per row, 128B (32 f32) each ----
    const int w_row = tid >> 1, w_half = tid & 1;
    const int wrow_g = min(n0 + w_row, N - 1);
    const float* __restrict__ Wf = W + (size_t)bz * strideW_mode
                                     + (size_t)wrow_g * K + w_half * 32;
    const int w_swz = (w_row & 7) << 4;

    float4 wreg[8];
    f32x4 acc[4][4];
#pragma unroll
    for (int i = 0; i < 4; ++i)
#pragma unroll
        for (int j = 0; j < 4; ++j)
#pragma unroll
            for (int r = 0; r < 4; ++r) acc[i][j][r] = 0.f;

    auto issueW = [&](int t) {
#pragma unroll
        for (int i = 0; i < 8; ++i) wreg[i] = *(const float4*)(Wf + t * 64 + i * 4);
    };
    auto writeW = [&](int buf) {
        unsigned char* Bb = &lds[buf][16384];
#pragma unroll
        for (int s = 0; s < 4; ++s) {
            uint4 v;
            v.x = cvt_pk_bf16(wreg[2 * s].x, wreg[2 * s].y);
            v.y = cvt_pk_bf16(wreg[2 * s].z, wreg[2 * s].w);
            v.z = cvt_pk_bf16(wreg[2 * s + 1].x, wreg[2 * s + 1].y);
            v.w = cvt_pk_bf16(wreg[2 * s + 1].z, wreg[2 * s + 1].w);
            *(uint4*)(&Bb[w_row * 128 + ((w_half * 64 + s * 16) ^ w_swz)]) = v;
        }
    };
    auto stageA = [&](int buf, int t) {
        unsigned char* Ab = &lds[buf][wid * 4096];
#pragma unroll
        for (int j = 0; j < 4; ++j)
            gl2lds16(aG + (size_t)j * a_jstep + t * 128, Ab + j * 1024);
    };

    // ---- prologue ----
    issueW(0);
    stageA(0, 0);
    writeW(0);
    __syncthreads();

    // ---- main loop: one barrier per K-step ----
#pragma unroll
    for (int t = 0; t < NSTEP; ++t) {
        const int cur = t & 1;
        if (t + 1 < NSTEP) {
            issueW(t + 1);
            stageA(cur ^ 1, t + 1);
        }
        {
            const unsigned char* Ab = &lds[cur][0];
            const unsigned char* Bb = &lds[cur][16384];
            const int swzf = (fr & 7) << 4;
#pragma unroll
            for (int kk = 0; kk < 2; ++kk) {
                const int cb = (kk * 64 + ks * 16) ^ swzf;
                s16x8 af[4], bfr[4];
#pragma unroll
                for (int mi = 0; mi < 4; ++mi)
                    af[mi] = *(const s16x8*)(Ab + (wr + mi * 16 + fr) * 128 + cb);
#pragma unroll
                for (int ni = 0; ni < 4; ++ni)
                    bfr[ni] = *(const s16x8*)(Bb + (wc + ni * 16 + fr) * 128 + cb);
#pragma unroll
                for (int mi = 0; mi < 4; ++mi)
#pragma unroll
                    for (int ni = 0; ni < 4; ++ni)
                        acc[mi][ni] = __builtin_amdgcn_mfma_f32_16x16x32_bf16(
                            af[mi], bfr[ni], acc[mi][ni], 0, 0, 0);
            }
        }
        if (t + 1 < NSTEP) writeW(cur ^ 1);
        __syncthreads();
    }

    // ---- epilogue ----
#pragma unroll
    for (int ni = 0; ni < 4; ++ni) {
        const int col = n0 + wc + ni * 16 + fr;
        if (col < N) {
            float bsum = 0.f;
            if (bias1) bsum += bias_scale * bias1[(size_t)bz * strideB_mode + col];
            if (bias2) bsum += bias2[(size_t)bz * strideB_mode + col];
#pragma unroll
            for (int mi = 0; mi < 4; ++mi) {
#pragma unroll
                for (int r = 0; r < 4; ++r) {
                    const int row = r0 + wr + mi * 16 + ks * 4 + r;
                    float v = acc[mi][ni][r] + bsum;
                    if (RELU) v = fmaxf(v, 0.f);
                    const size_t idx = (size_t)bz * strideC_mode + (size_t)row * ldc + col;
                    if (F32OUT) ((float*)Cv)[idx] = v;
                    else ((unsigned short*)Cv)[idx] = f2bf(v);
                }
            }
        }
    }
}

// ---------------------------------------------------------------------------
// Embedding: e[b,d] = mean_s emb[x[b,s], d]
// ---------------------------------------------------------------------------
__global__ __launch_bounds__(512) void embed_kernel(
    const int* __restrict__ x, const float* __restrict__ emb,
    unsigned short* __restrict__ e)
{
    const int b = blockIdx.x;
    __shared__ int xs[128];
    const int tid = threadIdx.x;
    if (tid < 128) xs[tid] = x[b * 128 + tid];
    __syncthreads();
    float s = 0.f;
    for (int i = 0; i < 128; ++i) s += emb[(size_t)xs[i] * 512 + tid];
    e[(size_t)b * 512 + tid] = f2bf(s * (1.f / 128.f));
}

// ---------------------------------------------------------------------------
// Row LayerNorm over D=512 (+opt ReLU), gamma/beta f32, m = row % M.
// ---------------------------------------------------------------------------
template<bool RELU>
__global__ __launch_bounds__(256) void ln_kernel(
    const unsigned short* __restrict__ X,
    const float* __restrict__ G,
    const float* __restrict__ Bt,
    unsigned short* __restrict__ Y,
    int M)
{
    const int row = blockIdx.x;
    const int m = row % M;
    const unsigned short* xr = X + (size_t)row * 512;
    unsigned short* yr = Y + (size_t)row * 512;
    const int tid = threadIdx.x;
    const float x0 = bf2f(xr[tid]), x1 = bf2f(xr[tid + 256]);
    float s = x0 + x1, q = x0 * x0 + x1 * x1;
#pragma unroll
    for (int off = 32; off; off >>= 1) {
        s += __shfl_xor(s, off);
        q += __shfl_xor(q, off);
    }
    __shared__ float red[4][2];
    const int wid = tid >> 6, lane = tid & 63;
    if (lane == 0) { red[wid][0] = s; red[wid][1] = q; }
    __syncthreads();
    s = red[0][0] + red[1][0] + red[2][0] + red[3][0];
    q = red[0][1] + red[1][1] + red[2][1] + red[3][1];
    const float mu = s * (1.f / 512.f);
    const float var = q * (1.f / 512.f) - mu * mu;
    const float rstd = rsqrtf(var + LN_EPS);
    const float* g = G + (size_t)m * 512;
    const float* bt = Bt + (size_t)m * 512;
    float y0 = (x0 - mu) * rstd * g[tid] + bt[tid];
    float y1 = (x1 - mu) * rstd * g[tid + 256] + bt[tid + 256];
    if (RELU) { y0 = fmaxf(y0, 0.f); y1 = fmaxf(y1, 0.f); }
    yr[tid] = f2bf(y0);
    yr[tid + 256] = f2bf(y1);
}

// ---------------------------------------------------------------------------
// MFMA attention: one block per (b, h), qkv [256,150,1536] bf16.
// ---------------------------------------------------------------------------
#define KP 72
#define VP 168
__global__ __launch_bounds__(256) void attn_mfma_kernel(
    const unsigned short* __restrict__ qkv, unsigned short* __restrict__ o_att)
{
    const int b = blockIdx.x >> 3, h = blockIdx.x & 7;
    __shared__ __align__(16) unsigned short k_s[160 * KP];
    __shared__ __align__(16) unsigned short v_t[64 * VP];
    __shared__ __align__(16) unsigned short p_s[4][16 * VP];
    const int tid = threadIdx.x, lane = tid & 63, wid = tid >> 6;
    const int fr = lane & 15, ks = lane >> 4;
    const size_t base = (size_t)b * (150 * 1536) + h * 64;

    for (int idx = tid; idx < 160 * 8; idx += 256) {
        const int r = idx >> 3, c8 = (idx & 7) * 8;
        u16x8 v;
        if (r < 150) v = *(const u16x8*)(qkv + base + (size_t)r * 1536 + 512 + c8);
        else {
#pragma unroll
            for (int j = 0; j < 8; ++j) v[j] = 0;
        }
        *(u16x8*)(&k_s[r * KP + c8]) = v;
    }
    for (int idx = tid; idx < 160 * 8; idx += 256) {
        const int c8 = idx / 160, r = idx - c8 * 160;
        u16x8 v;
        if (r < 150) v = *(const u16x8*)(qkv + base + (size_t)r * 1536 + 1024 + c8 * 8);
        else {
#pragma unroll
            for (int j = 0; j < 8; ++j) v[j] = 0;
        }
#pragma unroll
        for (int j = 0; j < 8; ++j) v_t[(c8 * 8 + j) * VP + r] = v[j];
    }
    __syncthreads();

    unsigned short* pw = &p_s[wid][0];

    for (int qt = wid; qt < 10; qt += 4) {
        const int qr = (qt * 16 + fr < 150) ? qt * 16 + fr : 149;
        const unsigned short* qp = qkv + base + (size_t)qr * 1536;
        s16x8 qa0 = *(const s16x8*)(qp + ks * 8);
        s16x8 qa1 = *(const s16x8*)(qp + 32 + ks * 8);

        f32x4 acc[10];
#pragma unroll
        for (int t = 0; t < 10; ++t)
#pragma unroll
            for (int r = 0; r < 4; ++r) acc[t][r] = 0.f;
#pragma unroll
        for (int t = 0; t < 10; ++t) {
            s16x8 kb0 = *(const s16x8*)(&k_s[(t * 16 + fr) * KP + ks * 8]);
            s16x8 kb1 = *(const s16x8*)(&k_s[(t * 16 + fr) * KP + 32 + ks * 8]);
            acc[t] = __builtin_amdgcn_mfma_f32_16x16x32_bf16(qa0, kb0, acc[t], 0, 0, 0);
            acc[t] = __builtin_amdgcn_mfma_f32_16x16x32_bf16(qa1, kb1, acc[t], 0, 0, 0);
        }

        const bool v9 = (fr < 6);
        float inv[4];
#pragma unroll
        for (int i = 0; i < 4; ++i) {
            float m = -1e30f;
#pragma unroll
            for (int t = 0; t < 9; ++t) m = fmaxf(m, acc[t][i]);
            if (v9) m = fmaxf(m, acc[9][i]);
#pragma unroll
            for (int off = 1; off < 16; off <<= 1) m = fmaxf(m, __shfl_xor(m, off));
            float s = 0.f;
#pragma unroll
            for (int t = 0; t < 10; ++t) {
                float e = 0.f;
                if (t < 9 || v9) e = __expf(0.125f * (acc[t][i] - m));
                s += e;
                pw[(ks * 4 + i) * VP + t * 16 + fr] = f2bf(e);
            }
#pragma unroll
            for (int off = 1; off < 16; off <<= 1) s += __shfl_xor(s, off);
            inv[i] = 1.f / s;
        }

        f32x4 o[4];
#pragma unroll
        for (int dt = 0; dt < 4; ++dt)
#pragma unroll
            for (int r = 0; r < 4; ++r) o[dt][r] = 0.f;
#pragma unroll
        for (int kc = 0; kc < 5; ++kc) {
            s16x8 pa = *(const s16x8*)(&pw[fr * VP + kc * 32 + ks * 8]);
#pragma unroll
            for (int dt = 0; dt < 4; ++dt) {
                s16x8 vb = *(const s16x8*)(&v_t[(dt * 16 + fr) * VP + kc * 32 + ks * 8]);
                o[dt] = __builtin_amdgcn_mfma_f32_16x16x32_bf16(pa, vb, o[dt], 0, 0, 0);
            }
        }

#pragma unroll
        for (int dt = 0; dt < 4; ++dt) {
            const int d = h * 64 + dt * 16 + fr;
#pragma unroll
            for (int i = 0; i < 4; ++i) {
                const int q = qt * 16 + ks * 4 + i;
                if (q < 150)
                    o_att[((size_t)(b * 150 + q)) * 512 + d] = f2bf(o[dt][i] * inv[i]);
            }
        }
    }
}

// ---------------------------------------------------------------------------
// osum[b,d] = sum_m o_att[b,m,d]
// ---------------------------------------------------------------------------
__global__ __launch_bounds__(512) void osum_kernel(
    const unsigned short* __restrict__ o_att, unsigned short* __restrict__ osum)
{
    const int b = blockIdx.x, tid = threadIdx.x;
    float s = 0.f;
    const unsigned short* p = o_att + (size_t)b * 150 * 512 + tid;
    for (int mm = 0; mm < 150; ++mm) s += bf2f(p[(size_t)mm * 512]);
    osum[(size_t)b * 512 + tid] = f2bf(s);
}

// ---------------------------------------------------------------------------
extern "C" void kernel_launch(void* const* d_in, const int* in_sizes, int n_in,
                              void* d_out, int out_size, void* d_ws, size_t ws_size,
                              hipStream_t stream)
{
    (void)in_sizes; (void)n_in; (void)out_size; (void)ws_size;

    const int*   x          = (const int*)d_in[0];
    const float* emb        = (const float*)d_in[1];
    const float* W1         = (const float*)d_in[2];
    const float* b1         = (const float*)d_in[3];
    const float* ln1_g      = (const float*)d_in[4];
    const float* ln1_b      = (const float*)d_in[5];
    const float* W2         = (const float*)d_in[6];
    const float* b2         = (const float*)d_in[7];
    const float* dbias      = (const float*)d_in[8];
    const float* in_proj_w  = (const float*)d_in[9];
    const float* in_proj_b  = (const float*)d_in[10];
    const float* out_proj_w = (const float*)d_in[11];
    const float* out_proj_b = (const float*)d_in[12];
    const float* norm_g     = (const float*)d_in[13];
    const float* norm_b     = (const float*)d_in[14];
    const float* dec_w1     = (const float*)d_in[15];
    const float* dec_b1     = (const float*)d_in[16];
    const float* dec_w2     = (const float*)d_in[17];
    const float* dec_b2     = (const float*)d_in[18];

    char* ws = (char*)d_ws;
    unsigned short* e_bf  = (unsigned short*)(ws + 0x0);        // [256,512] bf16
    unsigned short* osum  = (unsigned short*)(ws + 0x40000);
    unsigned short* att1  = (unsigned short*)(ws + 0x80000);
    unsigned short* agg   = (unsigned short*)(ws + 0xC0000);
    unsigned short* dec1  = (unsigned short*)(ws + 0x100000);
    unsigned short* h1    = (unsigned short*)(ws + 0x200000);   // [B,M,D] 37.5MB (later o_att)
    unsigned short* mo    = (unsigned short*)(ws + 0x2800000);  // [B,M,D] 37.5MB
    unsigned short* qkvf  = (unsigned short*)(ws + 0x4E00000);  // [B,M,3D] 112.5MB
    unsigned short* o_att = h1;

    // 1) embedding mean -> e [256,512]
    embed_kernel<<<256, 512, 0, stream>>>(x, emb, e_bf);

    // 2) G1: h1[b,m,:] = e[b,:] @ W1[m]^T + b1[m]   (gx=4, gy=2, gz=150)
    gemm128_kernel<512, false, false><<<4 * 2 * 150, 256, 0, stream>>>(
        e_bf, W1, b1, nullptr, 1.f, h1,
        512, 4, 2,
        (size_t)0, 512, (size_t)512 * 512, 512, 512, 76800);

    // 3) LN(ln1_g, ln1_b) + ReLU, in-place on h1
    ln_kernel<true><<<38400, 256, 0, stream>>>(h1, ln1_g, ln1_b, h1, 150);

    // 4) G2: mo = h1 @ W2^T + b2 + dbias
    gemm128_kernel<512, false, false><<<4 * 2 * 150, 256, 0, stream>>>(
        h1, W2, b2, dbias, 1.f, mo,
        512, 4, 2,
        (size_t)512, 76800, (size_t)512 * 512, 512, 512, 76800);

    // 5) qkv = mo @ in_proj_w^T + in_proj_b   (gx=12, gy=300)
    gemm128_kernel<512, false, false><<<12 * 300, 256, 0, stream>>>(
        mo, in_proj_w, in_proj_b, nullptr, 1.f, qkvf,
        1536, 12, 300,
        (size_t)0, 512, (size_t)0, 0, 0, 1536);

    // 6) attention per (b,h) -> o_att
    attn_mfma_kernel<<<2048, 256, 0, stream>>>(qkvf, o_att);

    // 7) osum[b,:] = sum_m o_att[b,m,:]
    osum_kernel<<<256, 512, 0, stream>>>(o_att, osum);

    // 8) attended_sum = osum @ out_proj_w^T + 150*out_proj_b
    gemm128_kernel<512, false, false><<<4 * 2, 256, 0, stream>>>(
        osum, out_proj_w, out_proj_b, nullptr, 150.f, att1,
        512, 4, 2,
        (size_t)0, 512, (size_t)0, 0, 0, 512);

    // 9) agg = LN(attended_sum; norm_g, norm_b)
    ln_kernel<false><<<256, 256, 0, stream>>>(att1, norm_g, norm_b, agg, 1);

    // 10) dec1 = ReLU(agg @ dec_w1^T + dec_b1)   [256,256]
    gemm128_kernel<512, true, false><<<2 * 2, 256, 0, stream>>>(
        agg, dec_w1, dec_b1, nullptr, 1.f, dec1,
        256, 2, 2,
        (size_t)0, 512, (size_t)0, 0, 0, 256);

    // 11) out = dec1 @ dec_w2^T + dec_b2   [256,10000] f32, K=256
    gemm128_kernel<256, false, true><<<79 * 2, 256, 0, stream>>>(
        dec1, dec_w2, dec_b2, nullptr, 1.f, d_out,
        10000, 79, 2,
        (size_t)0, 256, (size_t)0, 0, 0, 10000);
}

// Round 8
// 416.505 us; speedup vs baseline: 1.6309x; 1.2204x over previous
//
#include <hip/hip_runtime.h>

typedef __attribute__((ext_vector_type(8))) short s16x8;
typedef __attribute__((ext_vector_type(8))) unsigned short u16x8;
typedef __attribute__((ext_vector_type(4))) float f32x4;

#define LN_EPS 1e-5f

__device__ inline float bf2f(unsigned short u) {
    union { unsigned int i; float f; } x; x.i = ((unsigned int)u) << 16; return x.f;
}
__device__ inline unsigned short f2bf(float f) {
    unsigned int u = __builtin_bit_cast(unsigned int, f);
    u += 0x7FFFu + ((u >> 16) & 1u);
    return (unsigned short)(u >> 16);
}
__device__ inline unsigned int cvt_pk_bf16(float lo, float hi) {
    unsigned int r;
    asm("v_cvt_pk_bf16_f32 %0, %1, %2" : "=v"(r) : "v"(lo), "v"(hi));
    return r;
}
typedef __attribute__((address_space(1))) const unsigned int as1_u32;
typedef __attribute__((address_space(3))) unsigned int as3_u32;
__device__ inline void gl2lds16(const void* g, void* l) {
    __builtin_amdgcn_global_load_lds((as1_u32*)g, (as3_u32*)l, 16, 0, 0);
}

// ---------------------------------------------------------------------------
// BK=32 2-phase GEMM, BOTH operands staged via global_load_lds (w=16):
//   C[z] = A[z](bf16) @ W[z](f32)^T (+bias_scale*bias1+bias2)(+ReLU)
// 256 thr = 4 waves (2x2); tile 128(M) x 128(N); per buffer: A 8KB (bf16,
// linear) + B 16KB (f32, XOR-swizzled rows). 48KB LDS total -> 3 blocks/CU.
// W is staged as RAW F32 bytes; f32->bf16 conversion happens at ds_read time
// (v_cvt_pk_bf16_f32, hidden under MFMA). Staging = pure gl2lds, no VALU.
// M multiple of 128; N multiple of 8 (row-clamped staging + col-guarded out).
// ---------------------------------------------------------------------------
template<int K, bool RELU, bool F32OUT>
__global__ __launch_bounds__(256, 3) void gemm_k32_kernel(
    const unsigned short* __restrict__ A,
    const float* __restrict__ W,
    const float* __restrict__ bias1,
    const float* __restrict__ bias2,
    float bias_scale,
    void* __restrict__ Cv,
    int N, int gx, int gy,
    size_t strideA_mode, size_t lda,
    size_t strideW_mode, size_t strideB_mode,
    size_t strideC_mode, size_t ldc)
{
    constexpr int NSTEP = K / 32;   // even for K in {512, 256}

    // bijective XCD-aware remap (m204)
    const int nwg = gridDim.x, wgid = blockIdx.x;
    const int q8 = nwg >> 3, r8 = nwg & 7;
    const int xcd = wgid & 7, sub = wgid >> 3;
    int p = (xcd < r8 ? xcd * (q8 + 1) : r8 * (q8 + 1) + (xcd - r8) * q8) + sub;
    const int bx = p % gx; p /= gx;
    const int by = p % gy;
    const int bz = p / gy;
    const int n0 = bx * 128, r0 = by * 128;

    __shared__ __align__(16) unsigned char lds[2][24576];  // [A 8K | B-f32 16K]

    const int tid = threadIdx.x, lane = tid & 63, wid = tid >> 6;
    const int fr = lane & 15, ks = lane >> 4;
    const int wr = (wid >> 1) * 64, wc = (wid & 1) * 64;

    // ---- A staging coords (2 insts/thread): I = (wid*2+j)*64 + lane ----
    const int Ia0 = (wid * 2 + 0) * 64 + lane;
    const int Ia1 = (wid * 2 + 1) * 64 + lane;
    const unsigned char* Aslab = (const unsigned char*)(A + (size_t)bz * strideA_mode);
    const unsigned char* aSrc0 = Aslab + (size_t)(r0 + (Ia0 >> 2)) * lda * 2 + (Ia0 & 3) * 16;
    const unsigned char* aSrc1 = Aslab + (size_t)(r0 + (Ia1 >> 2)) * lda * 2 + (Ia1 & 3) * 16;

    // ---- B staging coords (4 insts/thread): I = (wid*4+j)*64 + lane ----
    const unsigned char* Wslab = (const unsigned char*)(W + (size_t)bz * strideW_mode);
    const unsigned char* bSrc[4];
#pragma unroll
    for (int j = 0; j < 4; ++j) {
        const int I = (wid * 4 + j) * 64 + lane;
        const int brow = I >> 3, bcp = I & 7;
        const int bcl = bcp ^ (brow & 7);
        const int growb = min(n0 + brow, N - 1);
        bSrc[j] = Wslab + (size_t)growb * K * 4 + bcl * 16;
    }

    f32x4 acc[4][4];
#pragma unroll
    for (int i = 0; i < 4; ++i)
#pragma unroll
        for (int j = 0; j < 4; ++j)
#pragma unroll
            for (int r = 0; r < 4; ++r) acc[i][j][r] = 0.f;

    auto stage = [&](int buf, int t) {
        unsigned char* Ad0 = &lds[buf][(wid * 2 + 0) * 1024];
        unsigned char* Ad1 = &lds[buf][(wid * 2 + 1) * 1024];
        gl2lds16(aSrc0 + (size_t)t * 64, Ad0);
        gl2lds16(aSrc1 + (size_t)t * 64, Ad1);
#pragma unroll
        for (int j = 0; j < 4; ++j)
            gl2lds16(bSrc[j] + (size_t)t * 128, &lds[buf][8192 + (wid * 4 + j) * 1024]);
    };

    auto compute = [&](int buf) {
        const unsigned char* Ab = &lds[buf][0];
        const unsigned char* Bb = &lds[buf][8192];
        s16x8 af[4];
#pragma unroll
        for (int mi = 0; mi < 4; ++mi)
            af[mi] = *(const s16x8*)(Ab + (wr + mi * 16 + fr) * 64 + ks * 16);
        s16x8 bfr[4];
#pragma unroll
        for (int ni = 0; ni < 4; ++ni) {
            const int brow = wc + ni * 16 + fr;
            const float4 v0 = *(const float4*)(Bb + brow * 128 + (((2 * ks + 0) ^ (fr & 7)) << 4));
            const float4 v1 = *(const float4*)(Bb + brow * 128 + (((2 * ks + 1) ^ (fr & 7)) << 4));
            union { unsigned int u[4]; s16x8 s; } r;
            r.u[0] = cvt_pk_bf16(v0.x, v0.y);
            r.u[1] = cvt_pk_bf16(v0.z, v0.w);
            r.u[2] = cvt_pk_bf16(v1.x, v1.y);
            r.u[3] = cvt_pk_bf16(v1.z, v1.w);
            bfr[ni] = r.s;
        }
#pragma unroll
        for (int mi = 0; mi < 4; ++mi)
#pragma unroll
            for (int ni = 0; ni < 4; ++ni)
                acc[mi][ni] = __builtin_amdgcn_mfma_f32_16x16x32_bf16(af[mi], bfr[ni], acc[mi][ni], 0, 0, 0);
    };

    // ---- prologue ----
    stage(0, 0);
    __syncthreads();

    // ---- main loop (NSTEP even): ping-pong, one barrier per K-step ----
    for (int t = 0; t < NSTEP; t += 2) {
        stage(1, t + 1);
        compute(0);
        __syncthreads();
        if (t + 2 < NSTEP) stage(0, t + 2);
        compute(1);
        __syncthreads();
    }

    // ---- epilogue ----
#pragma unroll
    for (int ni = 0; ni < 4; ++ni) {
        const int col = n0 + wc + ni * 16 + fr;
        if (col < N) {
            float bsum = 0.f;
            if (bias1) bsum += bias_scale * bias1[(size_t)bz * strideB_mode + col];
            if (bias2) bsum += bias2[(size_t)bz * strideB_mode + col];
#pragma unroll
            for (int mi = 0; mi < 4; ++mi) {
#pragma unroll
                for (int r = 0; r < 4; ++r) {
                    const int row = r0 + wr + mi * 16 + ks * 4 + r;
                    float v = acc[mi][ni][r] + bsum;
                    if (RELU) v = fmaxf(v, 0.f);
                    const size_t idx = (size_t)bz * strideC_mode + (size_t)row * ldc + col;
                    if (F32OUT) ((float*)Cv)[idx] = v;
                    else ((unsigned short*)Cv)[idx] = f2bf(v);
                }
            }
        }
    }
}

// ---------------------------------------------------------------------------
// Embedding: e[b,d] = mean_s emb[x[b,s], d]
// ---------------------------------------------------------------------------
__global__ __launch_bounds__(512) void embed_kernel(
    const int* __restrict__ x, const float* __restrict__ emb,
    unsigned short* __restrict__ e)
{
    const int b = blockIdx.x;
    __shared__ int xs[128];
    const int tid = threadIdx.x;
    if (tid < 128) xs[tid] = x[b * 128 + tid];
    __syncthreads();
    float s = 0.f;
    for (int i = 0; i < 128; ++i) s += emb[(size_t)xs[i] * 512 + tid];
    e[(size_t)b * 512 + tid] = f2bf(s * (1.f / 128.f));
}

// ---------------------------------------------------------------------------
// Row LayerNorm over D=512 (+opt ReLU), gamma/beta f32, m = row % M.
// ---------------------------------------------------------------------------
template<bool RELU>
__global__ __launch_bounds__(256) void ln_kernel(
    const unsigned short* __restrict__ X,
    const float* __restrict__ G,
    const float* __restrict__ Bt,
    unsigned short* __restrict__ Y,
    int M)
{
    const int row = blockIdx.x;
    const int m = row % M;
    const unsigned short* xr = X + (size_t)row * 512;
    unsigned short* yr = Y + (size_t)row * 512;
    const int tid = threadIdx.x;
    const float x0 = bf2f(xr[tid]), x1 = bf2f(xr[tid + 256]);
    float s = x0 + x1, q = x0 * x0 + x1 * x1;
#pragma unroll
    for (int off = 32; off; off >>= 1) {
        s += __shfl_xor(s, off);
        q += __shfl_xor(q, off);
    }
    __shared__ float red[4][2];
    const int wid = tid >> 6, lane = tid & 63;
    if (lane == 0) { red[wid][0] = s; red[wid][1] = q; }
    __syncthreads();
    s = red[0][0] + red[1][0] + red[2][0] + red[3][0];
    q = red[0][1] + red[1][1] + red[2][1] + red[3][1];
    const float mu = s * (1.f / 512.f);
    const float var = q * (1.f / 512.f) - mu * mu;
    const float rstd = rsqrtf(var + LN_EPS);
    const float* g = G + (size_t)m * 512;
    const float* bt = Bt + (size_t)m * 512;
    float y0 = (x0 - mu) * rstd * g[tid] + bt[tid];
    float y1 = (x1 - mu) * rstd * g[tid + 256] + bt[tid + 256];
    if (RELU) { y0 = fmaxf(y0, 0.f); y1 = fmaxf(y1, 0.f); }
    yr[tid] = f2bf(y0);
    yr[tid + 256] = f2bf(y1);
}

// ---------------------------------------------------------------------------
// MFMA attention: one block per (b, h), qkv [256,150,1536] bf16.
// ---------------------------------------------------------------------------
#define KP 72
#define VP 168
__global__ __launch_bounds__(256) void attn_mfma_kernel(
    const unsigned short* __restrict__ qkv, unsigned short* __restrict__ o_att)
{
    const int b = blockIdx.x >> 3, h = blockIdx.x & 7;
    __shared__ __align__(16) unsigned short k_s[160 * KP];
    __shared__ __align__(16) unsigned short v_t[64 * VP];
    __shared__ __align__(16) unsigned short p_s[4][16 * VP];
    const int tid = threadIdx.x, lane = tid & 63, wid = tid >> 6;
    const int fr = lane & 15, ks = lane >> 4;
    const size_t base = (size_t)b * (150 * 1536) + h * 64;

    for (int idx = tid; idx < 160 * 8; idx += 256) {
        const int r = idx >> 3, c8 = (idx & 7) * 8;
        u16x8 v;
        if (r < 150) v = *(const u16x8*)(qkv + base + (size_t)r * 1536 + 512 + c8);
        else {
#pragma unroll
            for (int j = 0; j < 8; ++j) v[j] = 0;
        }
        *(u16x8*)(&k_s[r * KP + c8]) = v;
    }
    for (int idx = tid; idx < 160 * 8; idx += 256) {
        const int c8 = idx / 160, r = idx - c8 * 160;
        u16x8 v;
        if (r < 150) v = *(const u16x8*)(qkv + base + (size_t)r * 1536 + 1024 + c8 * 8);
        else {
#pragma unroll
            for (int j = 0; j < 8; ++j) v[j] = 0;
        }
#pragma unroll
        for (int j = 0; j < 8; ++j) v_t[(c8 * 8 + j) * VP + r] = v[j];
    }
    __syncthreads();

    unsigned short* pw = &p_s[wid][0];

    for (int qt = wid; qt < 10; qt += 4) {
        const int qr = (qt * 16 + fr < 150) ? qt * 16 + fr : 149;
        const unsigned short* qp = qkv + base + (size_t)qr * 1536;
        s16x8 qa0 = *(const s16x8*)(qp + ks * 8);
        s16x8 qa1 = *(const s16x8*)(qp + 32 + ks * 8);

        f32x4 acc[10];
#pragma unroll
        for (int t = 0; t < 10; ++t)
#pragma unroll
            for (int r = 0; r < 4; ++r) acc[t][r] = 0.f;
#pragma unroll
        for (int t = 0; t < 10; ++t) {
            s16x8 kb0 = *(const s16x8*)(&k_s[(t * 16 + fr) * KP + ks * 8]);
            s16x8 kb1 = *(const s16x8*)(&k_s[(t * 16 + fr) * KP + 32 + ks * 8]);
            acc[t] = __builtin_amdgcn_mfma_f32_16x16x32_bf16(qa0, kb0, acc[t], 0, 0, 0);
            acc[t] = __builtin_amdgcn_mfma_f32_16x16x32_bf16(qa1, kb1, acc[t], 0, 0, 0);
        }

        const bool v9 = (fr < 6);
        float inv[4];
#pragma unroll
        for (int i = 0; i < 4; ++i) {
            float m = -1e30f;
#pragma unroll
            for (int t = 0; t < 9; ++t) m = fmaxf(m, acc[t][i]);
            if (v9) m = fmaxf(m, acc[9][i]);
#pragma unroll
            for (int off = 1; off < 16; off <<= 1) m = fmaxf(m, __shfl_xor(m, off));
            float s = 0.f;
#pragma unroll
            for (int t = 0; t < 10; ++t) {
                float e = 0.f;
                if (t < 9 || v9) e = __expf(0.125f * (acc[t][i] - m));
                s += e;
                pw[(ks * 4 + i) * VP + t * 16 + fr] = f2bf(e);
            }
#pragma unroll
            for (int off = 1; off < 16; off <<= 1) s += __shfl_xor(s, off);
            inv[i] = 1.f / s;
        }

        f32x4 o[4];
#pragma unroll
        for (int dt = 0; dt < 4; ++dt)
#pragma unroll
            for (int r = 0; r < 4; ++r) o[dt][r] = 0.f;
#pragma unroll
        for (int kc = 0; kc < 5; ++kc) {
            s16x8 pa = *(const s16x8*)(&pw[fr * VP + kc * 32 + ks * 8]);
#pragma unroll
            for (int dt = 0; dt < 4; ++dt) {
                s16x8 vb = *(const s16x8*)(&v_t[(dt * 16 + fr) * VP + kc * 32 + ks * 8]);
                o[dt] = __builtin_amdgcn_mfma_f32_16x16x32_bf16(pa, vb, o[dt], 0, 0, 0);
            }
        }

#pragma unroll
        for (int dt = 0; dt < 4; ++dt) {
            const int d = h * 64 + dt * 16 + fr;
#pragma unroll
            for (int i = 0; i < 4; ++i) {
                const int q = qt * 16 + ks * 4 + i;
                if (q < 150)
                    o_att[((size_t)(b * 150 + q)) * 512 + d] = f2bf(o[dt][i] * inv[i]);
            }
        }
    }
}

// ---------------------------------------------------------------------------
// osum[b,d] = sum_m o_att[b,m,d]
// ---------------------------------------------------------------------------
__global__ __launch_bounds__(512) void osum_kernel(
    const unsigned short* __restrict__ o_att, unsigned short* __restrict__ osum)
{
    const int b = blockIdx.x, tid = threadIdx.x;
    float s = 0.f;
    const unsigned short* p = o_att + (size_t)b * 150 * 512 + tid;
    for (int mm = 0; mm < 150; ++mm) s += bf2f(p[(size_t)mm * 512]);
    osum[(size_t)b * 512 + tid] = f2bf(s);
}

// ---------------------------------------------------------------------------
extern "C" void kernel_launch(void* const* d_in, const int* in_sizes, int n_in,
                              void* d_out, int out_size, void* d_ws, size_t ws_size,
                              hipStream_t stream)
{
    (void)in_sizes; (void)n_in; (void)out_size; (void)ws_size;

    const int*   x          = (const int*)d_in[0];
    const float* emb        = (const float*)d_in[1];
    const float* W1         = (const float*)d_in[2];
    const float* b1         = (const float*)d_in[3];
    const float* ln1_g      = (const float*)d_in[4];
    const float* ln1_b      = (const float*)d_in[5];
    const float* W2         = (const float*)d_in[6];
    const float* b2         = (const float*)d_in[7];
    const float* dbias      = (const float*)d_in[8];
    const float* in_proj_w  = (const float*)d_in[9];
    const float* in_proj_b  = (const float*)d_in[10];
    const float* out_proj_w = (const float*)d_in[11];
    const float* out_proj_b = (const float*)d_in[12];
    const float* norm_g     = (const float*)d_in[13];
    const float* norm_b     = (const float*)d_in[14];
    const float* dec_w1     = (const float*)d_in[15];
    const float* dec_b1     = (const float*)d_in[16];
    const float* dec_w2     = (const float*)d_in[17];
    const float* dec_b2     = (const float*)d_in[18];

    char* ws = (char*)d_ws;
    unsigned short* e_bf  = (unsigned short*)(ws + 0x0);        // [256,512] bf16
    unsigned short* osum  = (unsigned short*)(ws + 0x40000);
    unsigned short* att1  = (unsigned short*)(ws + 0x80000);
    unsigned short* agg   = (unsigned short*)(ws + 0xC0000);
    unsigned short* dec1  = (unsigned short*)(ws + 0x100000);
    unsigned short* h1    = (unsigned short*)(ws + 0x200000);   // [B,M,D] 37.5MB (later o_att)
    unsigned short* mo    = (unsigned short*)(ws + 0x2800000);  // [B,M,D] 37.5MB
    unsigned short* qkvf  = (unsigned short*)(ws + 0x4E00000);  // [B,M,3D] 112.5MB
    unsigned short* o_att = h1;

    // 1) embedding mean -> e [256,512]
    embed_kernel<<<256, 512, 0, stream>>>(x, emb, e_bf);

    // 2) G1: h1[b,m,:] = e[b,:] @ W1[m]^T + b1[m]   (gx=4, gy=2, gz=150)
    gemm_k32_kernel<512, false, false><<<4 * 2 * 150, 256, 0, stream>>>(
        e_bf, W1, b1, nullptr, 1.f, h1,
        512, 4, 2,
        (size_t)0, 512, (size_t)512 * 512, 512, 512, 76800);

    // 3) LN(ln1_g, ln1_b) + ReLU, in-place on h1
    ln_kernel<true><<<38400, 256, 0, stream>>>(h1, ln1_g, ln1_b, h1, 150);

    // 4) G2: mo = h1 @ W2^T + b2 + dbias
    gemm_k32_kernel<512, false, false><<<4 * 2 * 150, 256, 0, stream>>>(
        h1, W2, b2, dbias, 1.f, mo,
        512, 4, 2,
        (size_t)512, 76800, (size_t)512 * 512, 512, 512, 76800);

    // 5) qkv = mo @ in_proj_w^T + in_proj_b   (gx=12, gy=300)
    gemm_k32_kernel<512, false, false><<<12 * 300, 256, 0, stream>>>(
        mo, in_proj_w, in_proj_b, nullptr, 1.f, qkvf,
        1536, 12, 300,
        (size_t)0, 512, (size_t)0, 0, 0, 1536);

    // 6) attention per (b,h) -> o_att
    attn_mfma_kernel<<<2048, 256, 0, stream>>>(qkvf, o_att);

    // 7) osum[b,:] = sum_m o_att[b,m,:]
    osum_kernel<<<256, 512, 0, stream>>>(o_att, osum);

    // 8) attended_sum = osum @ out_proj_w^T + 150*out_proj_b
    gemm_k32_kernel<512, false, false><<<4 * 2, 256, 0, stream>>>(
        osum, out_proj_w, out_proj_b, nullptr, 150.f, att1,
        512, 4, 2,
        (size_t)0, 512, (size_t)0, 0, 0, 512);

    // 9) agg = LN(attended_sum; norm_g, norm_b)
    ln_kernel<false><<<256, 256, 0, stream>>>(att1, norm_g, norm_b, agg, 1);

    // 10) dec1 = ReLU(agg @ dec_w1^T + dec_b1)   [256,256]
    gemm_k32_kernel<512, true, false><<<2 * 2, 256, 0, stream>>>(
        agg, dec_w1, dec_b1, nullptr, 1.f, dec1,
        256, 2, 2,
        (size_t)0, 512, (size_t)0, 0, 0, 256);

    // 11) out = dec1 @ dec_w2^T + dec_b2   [256,10000] f32, K=256
    gemm_k32_kernel<256, false, true><<<79 * 2, 256, 0, stream>>>(
        dec1, dec_w2, dec_b2, nullptr, 1.f, d_out,
        10000, 79, 2,
        (size_t)0, 256, (size_t)0, 0, 0, 10000);
}

// Round 11
// 407.382 us; speedup vs baseline: 1.6674x; 1.0224x over previous
//
#include <hip/hip_runtime.h>

typedef __attribute__((ext_vector_type(8))) short s16x8;
typedef __attribute__((ext_vector_type(8))) unsigned short u16x8;
typedef __attribute__((ext_vector_type(4))) float f32x4;

#define LN_EPS 1e-5f

__device__ inline float bf2f(unsigned short u) {
    union { unsigned int i; float f; } x; x.i = ((unsigned int)u) << 16; return x.f;
}
__device__ inline unsigned short f2bf(float f) {
    unsigned int u = __builtin_bit_cast(unsigned int, f);
    u += 0x7FFFu + ((u >> 16) & 1u);
    return (unsigned short)(u >> 16);
}
__device__ inline unsigned int cvt_pk_bf16(float lo, float hi) {
    unsigned int r;
    asm("v_cvt_pk_bf16_f32 %0, %1, %2" : "=v"(r) : "v"(lo), "v"(hi));
    return r;
}
typedef __attribute__((address_space(1))) const unsigned int as1_u32;
typedef __attribute__((address_space(3))) unsigned int as3_u32;
__device__ inline void gl2lds16(const void* g, void* l) {
    __builtin_amdgcn_global_load_lds((as1_u32*)g, (as3_u32*)l, 16, 0, 0);
}

// ---------------------------------------------------------------------------
// BK=32 2-phase GEMM (round-8 proven sync: __syncthreads ping-pong), both
// operands staged via global_load_lds w=16:
//   C[z] = A[z](bf16) @ W[z](f32)^T (+bias_scale*bias1+bias2)(+ReLU)
// 256 thr = 4 waves (2x2); tile 128(M) x 128(N); per buffer: A 8KB bf16
// (SOURCE-XOR-swizzled chunk^(row&3), read ks^(fr&3) -> conflict-free) +
// B 16KB raw f32 (XOR rows). 48KB LDS -> 3 blocks/CU. f32->bf16 of B at
// ds_read time via v_cvt_pk_bf16_f32 (hidden under MFMA).
// Epilogue (bf16 out): LDS transpose -> 16B/lane contiguous stores.
// M multiple of 128; bf16-out N multiple of 128; f32-out N col-guarded.
// ---------------------------------------------------------------------------
template<int K, bool RELU, bool F32OUT>
__global__ __launch_bounds__(256, 3) void gemm_k32_kernel(
    const unsigned short* __restrict__ A,
    const float* __restrict__ W,
    const float* __restrict__ bias1,
    const float* __restrict__ bias2,
    float bias_scale,
    void* __restrict__ Cv,
    int N, int gx, int gy,
    size_t strideA_mode, size_t lda,
    size_t strideW_mode, size_t strideB_mode,
    size_t strideC_mode, size_t ldc)
{
    constexpr int NSTEP = K / 32;   // even for K in {512, 256}

    // bijective XCD-aware remap (m204)
    const int nwg = gridDim.x, wgid = blockIdx.x;
    const int q8 = nwg >> 3, r8 = nwg & 7;
    const int xcd = wgid & 7, sub = wgid >> 3;
    int p = (xcd < r8 ? xcd * (q8 + 1) : r8 * (q8 + 1) + (xcd - r8) * q8) + sub;
    const int bx = p % gx; p /= gx;
    const int by = p % gy;
    const int bz = p / gy;
    const int n0 = bx * 128, r0 = by * 128;

    __shared__ __align__(16) unsigned char lds[2][24576];  // [A 8K | B-f32 16K]

    const int tid = threadIdx.x, lane = tid & 63, wid = tid >> 6;
    const int fr = lane & 15, ks = lane >> 4;
    const int wr = (wid >> 1) * 64, wc = (wid & 1) * 64;

    // ---- A staging coords (2 insts/wave): I=(wid*2+j)*64+lane ----
    // dest linear (row*64 + (I&3)*16); SOURCE chunk XOR'd with row&3 (rule #21)
    const int Ia0 = (wid * 2 + 0) * 64 + lane;
    const int Ia1 = (wid * 2 + 1) * 64 + lane;
    const int ar0 = Ia0 >> 2, ac0 = (Ia0 & 3) ^ (ar0 & 3);
    const int ar1 = Ia1 >> 2, ac1 = (Ia1 & 3) ^ (ar1 & 3);
    const unsigned char* Aslab = (const unsigned char*)(A + (size_t)bz * strideA_mode);
    const unsigned char* aSrc0 = Aslab + (size_t)(r0 + ar0) * lda * 2 + ac0 * 16;
    const unsigned char* aSrc1 = Aslab + (size_t)(r0 + ar1) * lda * 2 + ac1 * 16;

    // ---- B staging coords (4 insts/wave): I=(wid*4+j)*64+lane ----
    const unsigned char* Wslab = (const unsigned char*)(W + (size_t)bz * strideW_mode);
    const unsigned char* bSrc[4];
#pragma unroll
    for (int j = 0; j < 4; ++j) {
        const int I = (wid * 4 + j) * 64 + lane;
        const int brow = I >> 3, bcp = I & 7;
        const int bcl = bcp ^ (brow & 7);
        const int growb = min(n0 + brow, N - 1);
        bSrc[j] = Wslab + (size_t)growb * K * 4 + bcl * 16;
    }

    f32x4 acc[4][4];
#pragma unroll
    for (int i = 0; i < 4; ++i)
#pragma unroll
        for (int j = 0; j < 4; ++j)
#pragma unroll
            for (int r = 0; r < 4; ++r) acc[i][j][r] = 0.f;

    auto stage = [&](int buf, int t) {
        gl2lds16(aSrc0 + (size_t)t * 64, &lds[buf][(wid * 2 + 0) * 1024]);
        gl2lds16(aSrc1 + (size_t)t * 64, &lds[buf][(wid * 2 + 1) * 1024]);
#pragma unroll
        for (int j = 0; j < 4; ++j)
            gl2lds16(bSrc[j] + (size_t)t * 128, &lds[buf][8192 + (wid * 4 + j) * 1024]);
    };

    auto compute = [&](int buf) {
        const unsigned char* Ab = &lds[buf][0];
        const unsigned char* Bb = &lds[buf][8192];
        s16x8 af[4];
#pragma unroll
        for (int mi = 0; mi < 4; ++mi)
            af[mi] = *(const s16x8*)(Ab + (wr + mi * 16 + fr) * 64 + ((ks ^ (fr & 3)) << 4));
        s16x8 bfr[4];
#pragma unroll
        for (int ni = 0; ni < 4; ++ni) {
            const int brow = wc + ni * 16 + fr;
            const float4 v0 = *(const float4*)(Bb + brow * 128 + (((2 * ks + 0) ^ (fr & 7)) << 4));
            const float4 v1 = *(const float4*)(Bb + brow * 128 + (((2 * ks + 1) ^ (fr & 7)) << 4));
            union { unsigned int u[4]; s16x8 s; } r;
            r.u[0] = cvt_pk_bf16(v0.x, v0.y);
            r.u[1] = cvt_pk_bf16(v0.z, v0.w);
            r.u[2] = cvt_pk_bf16(v1.x, v1.y);
            r.u[3] = cvt_pk_bf16(v1.z, v1.w);
            bfr[ni] = r.s;
        }
#pragma unroll
        for (int mi = 0; mi < 4; ++mi)
#pragma unroll
            for (int ni = 0; ni < 4; ++ni)
                acc[mi][ni] = __builtin_amdgcn_mfma_f32_16x16x32_bf16(af[mi], bfr[ni], acc[mi][ni], 0, 0, 0);
    };

    // ---- prologue ----
    stage(0, 0);
    __syncthreads();

    // ---- main loop (NSTEP even): ping-pong, __syncthreads (drains vmcnt) ----
    for (int t = 0; t < NSTEP; t += 2) {
        stage(1, t + 1);
        compute(0);
        __syncthreads();
        if (t + 2 < NSTEP) stage(0, t + 2);
        compute(1);
        __syncthreads();
    }

    // ---- epilogue ----
    if (!F32OUT) {
        // transpose through LDS -> contiguous 16B/lane stores (full sectors)
        unsigned short* Cl = (unsigned short*)&lds[0][0];   // 128x128 bf16
#pragma unroll
        for (int ni = 0; ni < 4; ++ni) {
            const int col = n0 + wc + ni * 16 + fr;
            float bsum = 0.f;
            if (bias1) bsum += bias_scale * bias1[(size_t)bz * strideB_mode + col];
            if (bias2) bsum += bias2[(size_t)bz * strideB_mode + col];
#pragma unroll
            for (int mi = 0; mi < 4; ++mi)
#pragma unroll
                for (int r = 0; r < 4; ++r) {
                    float v = acc[mi][ni][r] + bsum;
                    if (RELU) v = fmaxf(v, 0.f);
                    Cl[(wr + mi * 16 + ks * 4 + r) * 128 + wc + ni * 16 + fr] = f2bf(v);
                }
        }
        __syncthreads();
        unsigned short* Cg = (unsigned short*)Cv + (size_t)bz * strideC_mode;
#pragma unroll
        for (int it = 0; it < 8; ++it) {
            const int c = it * 256 + tid;
            const int row = c >> 4, ch = c & 15;
            u16x8 v = *(const u16x8*)(&Cl[row * 128 + ch * 8]);
            *(u16x8*)(Cg + (size_t)(r0 + row) * ldc + n0 + ch * 8) = v;
        }
    } else {
#pragma unroll
        for (int ni = 0; ni < 4; ++ni) {
            const int col = n0 + wc + ni * 16 + fr;
            if (col < N) {
                float bsum = 0.f;
                if (bias1) bsum += bias_scale * bias1[(size_t)bz * strideB_mode + col];
                if (bias2) bsum += bias2[(size_t)bz * strideB_mode + col];
#pragma unroll
                for (int mi = 0; mi < 4; ++mi)
#pragma unroll
                    for (int r = 0; r < 4; ++r) {
                        const int row = r0 + wr + mi * 16 + ks * 4 + r;
                        float v = acc[mi][ni][r] + bsum;
                        if (RELU) v = fmaxf(v, 0.f);
                        ((float*)Cv)[(size_t)bz * strideC_mode + (size_t)row * ldc + col] = v;
                    }
            }
        }
    }
}

// ---------------------------------------------------------------------------
// Embedding: e[b,d] = mean_s emb[x[b,s], d]
// ---------------------------------------------------------------------------
__global__ __launch_bounds__(512) void embed_kernel(
    const int* __restrict__ x, const float* __restrict__ emb,
    unsigned short* __restrict__ e)
{
    const int b = blockIdx.x;
    __shared__ int xs[128];
    const int tid = threadIdx.x;
    if (tid < 128) xs[tid] = x[b * 128 + tid];
    __syncthreads();
    float s = 0.f;
    for (int i = 0; i < 128; ++i) s += emb[(size_t)xs[i] * 512 + tid];
    e[(size_t)b * 512 + tid] = f2bf(s * (1.f / 128.f));
}

// ---------------------------------------------------------------------------
// Row LayerNorm over D=512 (+opt ReLU), gamma/beta f32, m = row % M.
// ---------------------------------------------------------------------------
template<bool RELU>
__global__ __launch_bounds__(256) void ln_kernel(
    const unsigned short* __restrict__ X,
    const float* __restrict__ G,
    const float* __restrict__ Bt,
    unsigned short* __restrict__ Y,
    int M)
{
    const int row = blockIdx.x;
    const int m = row % M;
    const unsigned short* xr = X + (size_t)row * 512;
    unsigned short* yr = Y + (size_t)row * 512;
    const int tid = threadIdx.x;
    const float x0 = bf2f(xr[tid]), x1 = bf2f(xr[tid + 256]);
    float s = x0 + x1, q = x0 * x0 + x1 * x1;
#pragma unroll
    for (int off = 32; off; off >>= 1) {
        s += __shfl_xor(s, off);
        q += __shfl_xor(q, off);
    }
    __shared__ float red[4][2];
    const int wid = tid >> 6, lane = tid & 63;
    if (lane == 0) { red[wid][0] = s; red[wid][1] = q; }
    __syncthreads();
    s = red[0][0] + red[1][0] + red[2][0] + red[3][0];
    q = red[0][1] + red[1][1] + red[2][1] + red[3][1];
    const float mu = s * (1.f / 512.f);
    const float var = q * (1.f / 512.f) - mu * mu;
    const float rstd = rsqrtf(var + LN_EPS);
    const float* g = G + (size_t)m * 512;
    const float* bt = Bt + (size_t)m * 512;
    float y0 = (x0 - mu) * rstd * g[tid] + bt[tid];
    float y1 = (x1 - mu) * rstd * g[tid + 256] + bt[tid + 256];
    if (RELU) { y0 = fmaxf(y0, 0.f); y1 = fmaxf(y1, 0.f); }
    yr[tid] = f2bf(y0);
    yr[tid + 256] = f2bf(y1);
}

// ---------------------------------------------------------------------------
// MFMA attention: one block per (b, h), qkv [256,150,1536] bf16.
// ---------------------------------------------------------------------------
#define KP 72
#define VP 168
__global__ __launch_bounds__(256) void attn_mfma_kernel(
    const unsigned short* __restrict__ qkv, unsigned short* __restrict__ o_att)
{
    const int b = blockIdx.x >> 3, h = blockIdx.x & 7;
    __shared__ __align__(16) unsigned short k_s[160 * KP];
    __shared__ __align__(16) unsigned short v_t[64 * VP];
    __shared__ __align__(16) unsigned short p_s[4][16 * VP];
    const int tid = threadIdx.x, lane = tid & 63, wid = tid >> 6;
    const int fr = lane & 15, ks = lane >> 4;
    const size_t base = (size_t)b * (150 * 1536) + h * 64;

    for (int idx = tid; idx < 160 * 8; idx += 256) {
        const int r = idx >> 3, c8 = (idx & 7) * 8;
        u16x8 v;
        if (r < 150) v = *(const u16x8*)(qkv + base + (size_t)r * 1536 + 512 + c8);
        else {
#pragma unroll
            for (int j = 0; j < 8; ++j) v[j] = 0;
        }
        *(u16x8*)(&k_s[r * KP + c8]) = v;
    }
    for (int idx = tid; idx < 160 * 8; idx += 256) {
        const int c8 = idx / 160, r = idx - c8 * 160;
        u16x8 v;
        if (r < 150) v = *(const u16x8*)(qkv + base + (size_t)r * 1536 + 1024 + c8 * 8);
        else {
#pragma unroll
            for (int j = 0; j < 8; ++j) v[j] = 0;
        }
#pragma unroll
        for (int j = 0; j < 8; ++j) v_t[(c8 * 8 + j) * VP + r] = v[j];
    }
    __syncthreads();

    unsigned short* pw = &p_s[wid][0];

    for (int qt = wid; qt < 10; qt += 4) {
        const int qr = (qt * 16 + fr < 150) ? qt * 16 + fr : 149;
        const unsigned short* qp = qkv + base + (size_t)qr * 1536;
        s16x8 qa0 = *(const s16x8*)(qp + ks * 8);
        s16x8 qa1 = *(const s16x8*)(qp + 32 + ks * 8);

        f32x4 acc[10];
#pragma unroll
        for (int t = 0; t < 10; ++t)
#pragma unroll
            for (int r = 0; r < 4; ++r) acc[t][r] = 0.f;
#pragma unroll
        for (int t = 0; t < 10; ++t) {
            s16x8 kb0 = *(const s16x8*)(&k_s[(t * 16 + fr) * KP + ks * 8]);
            s16x8 kb1 = *(const s16x8*)(&k_s[(t * 16 + fr) * KP + 32 + ks * 8]);
            acc[t] = __builtin_amdgcn_mfma_f32_16x16x32_bf16(qa0, kb0, acc[t], 0, 0, 0);
            acc[t] = __builtin_amdgcn_mfma_f32_16x16x32_bf16(qa1, kb1, acc[t], 0, 0, 0);
        }

        const bool v9 = (fr < 6);
        float inv[4];
#pragma unroll
        for (int i = 0; i < 4; ++i) {
            float m = -1e30f;
#pragma unroll
            for (int t = 0; t < 9; ++t) m = fmaxf(m, acc[t][i]);
            if (v9) m = fmaxf(m, acc[9][i]);
#pragma unroll
            for (int off = 1; off < 16; off <<= 1) m = fmaxf(m, __shfl_xor(m, off));
            float s = 0.f;
#pragma unroll
            for (int t = 0; t < 10; ++t) {
                float e = 0.f;
                if (t < 9 || v9) e = __expf(0.125f * (acc[t][i] - m));
                s += e;
                pw[(ks * 4 + i) * VP + t * 16 + fr] = f2bf(e);
            }
#pragma unroll
            for (int off = 1; off < 16; off <<= 1) s += __shfl_xor(s, off);
            inv[i] = 1.f / s;
        }

        f32x4 o[4];
#pragma unroll
        for (int dt = 0; dt < 4; ++dt)
#pragma unroll
            for (int r = 0; r < 4; ++r) o[dt][r] = 0.f;
#pragma unroll
        for (int kc = 0; kc < 5; ++kc) {
            s16x8 pa = *(const s16x8*)(&pw[fr * VP + kc * 32 + ks * 8]);
#pragma unroll
            for (int dt = 0; dt < 4; ++dt) {
                s16x8 vb = *(const s16x8*)(&v_t[(dt * 16 + fr) * VP + kc * 32 + ks * 8]);
                o[dt] = __builtin_amdgcn_mfma_f32_16x16x32_bf16(pa, vb, o[dt], 0, 0, 0);
            }
        }

#pragma unroll
        for (int dt = 0; dt < 4; ++dt) {
            const int d = h * 64 + dt * 16 + fr;
#pragma unroll
            for (int i = 0; i < 4; ++i) {
                const int q = qt * 16 + ks * 4 + i;
                if (q < 150)
                    o_att[((size_t)(b * 150 + q)) * 512 + d] = f2bf(o[dt][i] * inv[i]);
            }
        }
    }
}

// ---------------------------------------------------------------------------
// osum[b,d] = sum_m o_att[b,m,d]
// ---------------------------------------------------------------------------
__global__ __launch_bounds__(512) void osum_kernel(
    const unsigned short* __restrict__ o_att, unsigned short* __restrict__ osum)
{
    const int b = blockIdx.x, tid = threadIdx.x;
    float s = 0.f;
    const unsigned short* p = o_att + (size_t)b * 150 * 512 + tid;
    for (int mm = 0; mm < 150; ++mm) s += bf2f(p[(size_t)mm * 512]);
    osum[(size_t)b * 512 + tid] = f2bf(s);
}

// ---------------------------------------------------------------------------
extern "C" void kernel_launch(void* const* d_in, const int* in_sizes, int n_in,
                              void* d_out, int out_size, void* d_ws, size_t ws_size,
                              hipStream_t stream)
{
    (void)in_sizes; (void)n_in; (void)out_size; (void)ws_size;

    const int*   x          = (const int*)d_in[0];
    const float* emb        = (const float*)d_in[1];
    const float* W1         = (const float*)d_in[2];
    const float* b1         = (const float*)d_in[3];
    const float* ln1_g      = (const float*)d_in[4];
    const float* ln1_b      = (const float*)d_in[5];
    const float* W2         = (const float*)d_in[6];
    const float* b2         = (const float*)d_in[7];
    const float* dbias      = (const float*)d_in[8];
    const float* in_proj_w  = (const float*)d_in[9];
    const float* in_proj_b  = (const float*)d_in[10];
    const float* out_proj_w = (const float*)d_in[11];
    const float* out_proj_b = (const float*)d_in[12];
    const float* norm_g     = (const float*)d_in[13];
    const float* norm_b     = (const float*)d_in[14];
    const float* dec_w1     = (const float*)d_in[15];
    const float* dec_b1     = (const float*)d_in[16];
    const float* dec_w2     = (const float*)d_in[17];
    const float* dec_b2     = (const float*)d_in[18];

    char* ws = (char*)d_ws;
    unsigned short* e_bf  = (unsigned short*)(ws + 0x0);        // [256,512] bf16
    unsigned short* osum  = (unsigned short*)(ws + 0x40000);
    unsigned short* att1  = (unsigned short*)(ws + 0x80000);
    unsigned short* agg   = (unsigned short*)(ws + 0xC0000);
    unsigned short* dec1  = (unsigned short*)(ws + 0x100000);
    unsigned short* h1    = (unsigned short*)(ws + 0x200000);   // [B,M,D] 37.5MB (later o_att)
    unsigned short* mo    = (unsigned short*)(ws + 0x2800000);  // [B,M,D] 37.5MB
    unsigned short* qkvf  = (unsigned short*)(ws + 0x4E00000);  // [B,M,3D] 112.5MB
    unsigned short* o_att = h1;

    // 1) embedding mean -> e [256,512]
    embed_kernel<<<256, 512, 0, stream>>>(x, emb, e_bf);

    // 2) G1: h1[b,m,:] = e[b,:] @ W1[m]^T + b1[m]   (gx=4, gy=2, gz=150)
    gemm_k32_kernel<512, false, false><<<4 * 2 * 150, 256, 0, stream>>>(
        e_bf, W1, b1, nullptr, 1.f, h1,
        512, 4, 2,
        (size_t)0, 512, (size_t)512 * 512, 512, 512, 76800);

    // 3) LN(ln1_g, ln1_b) + ReLU, in-place on h1
    ln_kernel<true><<<38400, 256, 0, stream>>>(h1, ln1_g, ln1_b, h1, 150);

    // 4) G2: mo = h1 @ W2^T + b2 + dbias
    gemm_k32_kernel<512, false, false><<<4 * 2 * 150, 256, 0, stream>>>(
        h1, W2, b2, dbias, 1.f, mo,
        512, 4, 2,
        (size_t)512, 76800, (size_t)512 * 512, 512, 512, 76800);

    // 5) qkv = mo @ in_proj_w^T + in_proj_b   (gx=12, gy=300)
    gemm_k32_kernel<512, false, false><<<12 * 300, 256, 0, stream>>>(
        mo, in_proj_w, in_proj_b, nullptr, 1.f, qkvf,
        1536, 12, 300,
        (size_t)0, 512, (size_t)0, 0, 0, 1536);

    // 6) attention per (b,h) -> o_att
    attn_mfma_kernel<<<2048, 256, 0, stream>>>(qkvf, o_att);

    // 7) osum[b,:] = sum_m o_att[b,m,:]
    osum_kernel<<<256, 512, 0, stream>>>(o_att, osum);

    // 8) attended_sum = osum @ out_proj_w^T + 150*out_proj_b
    gemm_k32_kernel<512, false, false><<<4 * 2, 256, 0, stream>>>(
        osum, out_proj_w, out_proj_b, nullptr, 150.f, att1,
        512, 4, 2,
        (size_t)0, 512, (size_t)0, 0, 0, 512);

    // 9) agg = LN(attended_sum; norm_g, norm_b)
    ln_kernel<false><<<256, 256, 0, stream>>>(att1, norm_g, norm_b, agg, 1);

    // 10) dec1 = ReLU(agg @ dec_w1^T + dec_b1)   [256,256]
    gemm_k32_kernel<512, true, false><<<2 * 2, 256, 0, stream>>>(
        agg, dec_w1, dec_b1, nullptr, 1.f, dec1,
        256, 2, 2,
        (size_t)0, 512, (size_t)0, 0, 0, 256);

    // 11) out = dec1 @ dec_w2^T + dec_b2   [256,10000] f32, K=256
    gemm_k32_kernel<256, false, true><<<79 * 2, 256, 0, stream>>>(
        dec1, dec_w2, dec_b2, nullptr, 1.f, d_out,
        10000, 79, 2,
        (size_t)0, 256, (size_t)0, 0, 0, 10000);
}